// Round 9
// baseline (206.863 us; speedup 1.0000x reference)
//
#include <hip/hip_runtime.h>
#include <hip/hip_bf16.h>
#include <math.h>

#define SEQ 720
#define NCH 128
#define BATCH 128
#define BN 16384
#define DOM 72
#define PIN 30
#define POUT 30
#define FRQ 33
#define EMB 64
#define PER 24
#define KW 990
#define KP 1728
#define MT 768
#define PI_F 3.14159265358979323846f

typedef float2 cf;
__device__ __forceinline__ cf cmac(cf acc, cf a, cf b){
  acc.x += a.x*b.x - a.y*b.y; acc.y += a.x*b.y + a.y*b.x; return acc;
}
__device__ __forceinline__ short b2s(float f){
  __hip_bfloat16 h = __float2bfloat16(f);
  return *reinterpret_cast<short*>(&h);
}

// ---------------- P15: block 72 = p1 weight-composition; blocks 0..71 = p5 A1 rows ----------------
__global__ __launch_bounds__(256) void p15(const float* __restrict__ WPW, const float* __restrict__ WPb,
                         const float* __restrict__ m1r, const float* __restrict__ m1i,
                         const float* __restrict__ m1br, const float* __restrict__ m1bi,
                         const float* __restrict__ fxr, const float* __restrict__ fxi,
                         const float* __restrict__ fxbr, const float* __restrict__ fxbi,
                         const float* __restrict__ pjr, const float* __restrict__ pji,
                         const float* __restrict__ pjbr, const float* __restrict__ pjbi,
                         const float* __restrict__ fqr, const float* __restrict__ fqi,
                         cf* C, cf* PM, cf* M2, cf* o3b,
                         float* __restrict__ A1r, float* __restrict__ A1i)
{
  // p1 LDS
  __shared__ cf e64[64];
  __shared__ float sW[EMB*PER];
  __shared__ float sWb[EMB];
  __shared__ float sM1r[PIN*PIN], sM1i[PIN*PIN];
  __shared__ float sFxr[FRQ*FRQ], sFxi[FRQ*FRQ];
  __shared__ float sPjr[POUT*PIN], sPji[POUT*PIN];
  __shared__ float sB[6*33];
  __shared__ cf s_d[FRQ];
  __shared__ cf s_rs[PIN];
  __shared__ cf s_o1[FRQ*PIN];
  __shared__ cf s_o2[FRQ*PIN];
  // p5 LDS
  __shared__ cf tbl[720];
  __shared__ cf wrow[DOM];

  int tid = threadIdx.x;
  if (blockIdx.x < DOM){
    // ---- p5 path: A1[k][tau] ----
    int k = blockIdx.x;
    for (int m=tid;m<720;m+=256){ float s,c; sincosf(-2.f*PI_F*(float)m/720.f,&s,&c); tbl[m]=make_float2(c,s); }
    for (int j=tid;j<DOM;j+=256) wrow[j]=make_float2(fqr[k*DOM+j], fqi[k*DOM+j]);
    __syncthreads();
    for (int tau=tid; tau<720; tau+=256){
      cf acc=make_float2(0.f,0.f);
      for (int j=0;j<DOM;++j) acc = cmac(acc, wrow[j], tbl[(j*tau)%720]);
      A1r[k*720+tau]=acc.x;
      A1i[k*720+tau]=acc.y;
    }
    return;
  }
  // ---- p1 path ----
  if (tid < 64){ float s,c; sincosf(2.f*PI_F*tid/64.f, &s, &c); e64[tid] = make_float2(c, s); }
  for (int i=tid; i<EMB*PER; i+=256) sW[i]=WPW[i];
  if (tid < EMB) sWb[tid]=WPb[tid];
  for (int i=tid; i<PIN*PIN; i+=256){ sM1r[i]=m1r[i]; sM1i[i]=m1i[i]; sPjr[i]=pjr[i]; sPji[i]=pji[i]; }
  for (int i=tid; i<FRQ*FRQ; i+=256){ sFxr[i]=fxr[i]; sFxi[i]=fxi[i]; }
  if (tid < PIN)  { sB[tid]      = m1br[tid]; sB[33+tid]  = m1bi[tid]; }
  if (tid < FRQ)  { sB[66+tid]   = fxbr[tid]; sB[99+tid]  = fxbi[tid]; }
  if (tid < POUT) { sB[132+tid]  = pjbr[tid]; sB[165+tid] = pjbi[tid]; }
  __syncthreads();
  for (int idx=tid; idx<FRQ*PER; idx+=256){
    int f = idx/PER, i = idx%PER;
    cf acc = make_float2(0.f,0.f);
    #pragma unroll 8
    for (int o=0;o<EMB;++o){ cf e = e64[(f*o)&63]; float w = sW[o*PER+i]; acc.x += w*e.x; acc.y -= w*e.y; }
    C[idx] = acc;
  }
  for (int f=tid; f<FRQ; f+=256){
    cf acc = make_float2(0.f,0.f);
    #pragma unroll 8
    for (int o=0;o<EMB;++o){ cf e = e64[(f*o)&63]; acc.x += sWb[o]*e.x; acc.y -= sWb[o]*e.y; }
    s_d[f]=acc;
  }
  for (int idx=tid; idx<POUT*PIN; idx+=256){
    int q = idx/PIN, pp = idx%PIN;
    cf acc = make_float2(sPjr[q*PIN+pp], sPji[q*PIN+pp]);
    #pragma unroll 6
    for (int p=0;p<PIN;++p){
      cf a = make_float2(sPjr[q*PIN+p], sPji[q*PIN+p]);
      cf b = make_float2(sM1r[p*PIN+pp], sM1i[p*PIN+pp]);
      acc = cmac(acc, a, b);
    }
    PM[idx]=acc;
  }
  for (int idx=tid; idx<FRQ*FRQ; idx+=256){
    int f = idx/FRQ, ff = idx%FRQ;
    cf v = make_float2(sFxr[idx], sFxi[idx]); if (f==ff) v.x += 1.f;
    M2[idx]=v;
  }
  for (int p=tid; p<PIN; p+=256){
    cf acc = make_float2(1.f,0.f);
    #pragma unroll 6
    for (int pp=0;pp<PIN;++pp){ acc.x += sM1r[p*PIN+pp]; acc.y += sM1i[p*PIN+pp]; }
    s_rs[p]=acc;
  }
  __syncthreads();
  for (int idx=tid; idx<FRQ*PIN; idx+=256){
    int f = idx/PIN, p = idx%PIN;
    cf v = make_float2(0.f,0.f); v = cmac(v, s_d[f], s_rs[p]);
    v.x += sB[p]; v.y += sB[33+p];
    s_o1[idx]=v;
  }
  __syncthreads();
  for (int idx=tid; idx<FRQ*PIN; idx+=256){
    int f = idx/PIN, p = idx%PIN;
    cf acc = make_float2(sB[66+f], sB[99+f]);
    #pragma unroll 4
    for (int ff=0; ff<FRQ; ++ff){
      cf m2 = make_float2(sFxr[f*FRQ+ff], sFxi[f*FRQ+ff]); if (f==ff) m2.x += 1.f;
      acc = cmac(acc, m2, s_o1[ff*PIN+p]);
    }
    s_o2[idx]=acc;
  }
  __syncthreads();
  for (int idx=tid; idx<FRQ*POUT; idx+=256){
    int f = idx/POUT, q = idx%POUT;
    cf acc = make_float2(sB[132+q], sB[165+q]);
    #pragma unroll 6
    for (int p=0;p<PIN;++p){
      cf a = make_float2(sPjr[q*PIN+p], sPji[q*PIN+p]);
      acc = cmac(acc, a, s_o2[f*PIN+p]);
    }
    o3b[f*POUT+q]=acc;
  }
}

// ---------------- P5M: Mlow[t][tau] = sum_k Gr[t,k]A1r[k,tau] - Gi[t,k]A1i[k,tau]
__global__ __launch_bounds__(256) void p5m_mlow(const float* __restrict__ A1r,
                                                const float* __restrict__ A1i,
                                                float* __restrict__ Mlow){
  __shared__ float sG[16*144];
  __shared__ float sA[144*16];
  int t0 = blockIdx.y*16, tau0 = blockIdx.x*16;
  int tid = threadIdx.x;
  for (int i=tid; i<16*72; i+=256){
    int tt=i/72, k=i%72;
    int m = ((t0+tt)*k) % 720;
    float s,c; sincosf(2.f*PI_F*(float)m/720.f,&s,&c);
    float sc = (k==0)?(1.f/720.f):(2.f/720.f);
    sG[tt*144+k]    = c*sc;
    sG[tt*144+72+k] = s*sc;
  }
  for (int i=tid; i<72*16; i+=256){
    int k=i/16, tc=i%16;
    sA[k*16+tc]      = A1r[k*720+tau0+tc];
    sA[(72+k)*16+tc] = A1i[k*720+tau0+tc];
  }
  __syncthreads();
  int tt=tid/16, tc=tid%16;
  float acc=0.f;
  #pragma unroll 8
  for (int k=0;k<72;++k)
    acc += sG[tt*144+k]*sA[k*16+tc] - sG[tt*144+72+k]*sA[(72+k)*16+tc];
  Mlow[(size_t)(t0+tt)*720 + tau0+tc] = acc;
}

// ---------------- P_BIG: per-t merged p2+p3+p4+p7 -> V[t], bias[t] ----------------
__global__ __launch_bounds__(256) void p_big(const float* __restrict__ hW,
                    const cf* __restrict__ PM, const cf* __restrict__ M2, const cf* __restrict__ o3b,
                    const float* __restrict__ fbr, const float* __restrict__ fbi,
                    const float* __restrict__ headb,
                    cf* __restrict__ V, float* __restrict__ bias){
  __shared__ cf e64[64];
  __shared__ float shw[1920];
  __shared__ cf sHc[990];
  __shared__ cf sV1[990];
  __shared__ cf sPM[POUT*PIN];
  __shared__ cf sM2[FRQ*FRQ];
  __shared__ cf sO3[FRQ*POUT];
  __shared__ float red[256];
  int tid=threadIdx.x; int t=blockIdx.x;
  if (tid<64){ float s,c; sincosf(2.f*PI_F*tid/64.f,&s,&c); e64[tid]=make_float2(c,s); }
  for (int i=tid;i<1920;i+=256) shw[i]=hW[(size_t)t*1920+i];
  for (int i=tid;i<POUT*PIN;i+=256) sPM[i]=PM[i];
  for (int i=tid;i<FRQ*FRQ;i+=256) sM2[i]=M2[i];
  for (int i=tid;i<FRQ*POUT;i+=256) sO3[i]=o3b[i];
  __syncthreads();
  for (int idx=tid; idx<990; idx+=256){
    int q=idx/FRQ, f=idx%FRQ;
    cf acc=make_float2(0.f,0.f);
    const float* hw = &shw[q*64];
    for (int o=0;o<EMB;++o){ cf e=e64[(f*o)&63]; float w=hw[o]; acc.x+=w*e.x; acc.y+=w*e.y; }
    float s=((f==0)||(f==32))?(1.f/64.f):(2.f/64.f);
    sHc[idx]=make_float2(acc.x*s, acc.y*s);
  }
  __syncthreads();
  for (int idx=tid; idx<990; idx+=256){
    int f=idx/PIN, p=idx%PIN;
    cf acc=make_float2(0.f,0.f);
    for (int q=0;q<POUT;++q) acc=cmac(acc, sHc[q*FRQ+f], sPM[q*PIN+p]);
    sV1[idx]=acc;
  }
  __syncthreads();
  for (int idx=tid; idx<990; idx+=256){
    int ff=idx/PIN, pp=idx%PIN;
    cf acc=make_float2(0.f,0.f);
    for (int f=0;f<FRQ;++f) acc=cmac(acc, sV1[f*PIN+pp], sM2[f*FRQ+ff]);
    V[(size_t)t*990+idx]=acc;
  }
  float part=0.f;
  for (int idx=tid; idx<990; idx+=256){
    int q=idx/FRQ, f=idx%FRQ;
    cf h=sHc[idx]; cf o=sO3[f*POUT+q];
    part += h.x*o.x - h.y*o.y;
  }
  part *= 0.7f;
  if (tid<DOM){
    int m=(tid*t)%720; float s,c; sincosf(2.f*PI_F*(float)m/720.f,&s,&c);
    float sc=(tid==0)?(1.f/720.f):(2.f/720.f);
    part += 0.3f*sc*(c*fbr[tid] - s*fbi[tid]);
  }
  red[tid]=part; __syncthreads();
  for (int s=128;s>0;s>>=1){ if (tid<s) red[tid]+=red[tid+s]; __syncthreads(); }
  if (tid==0) bias[t] = red[0] + 0.7f*headb[t];
}

// ---------------- P6: build fused bf16 weight row t ----------------
__global__ void p6_bt(const cf* __restrict__ V, const cf* __restrict__ C,
                      const float* __restrict__ Mlow, __hip_bfloat16* __restrict__ BTm){
  __shared__ cf sV[990];
  __shared__ cf sC[FRQ*PER];
  int tid=threadIdx.x; int t=blockIdx.x;
  for (int i=tid;i<990;i+=256) sV[i]=V[(size_t)t*990+i];
  for (int i=tid;i<FRQ*PER;i+=256) sC[i]=C[i];
  __syncthreads();
  const float* ml = Mlow + (size_t)t*720;
  for (int tau=tid; tau<720; tau+=256){
    int p0 = tau/PER, i0 = tau - p0*PER;
    float mper=0.f;
    for (int f=0; f<FRQ; ++f){ cf v=sV[f*PIN+p0]; cf c=sC[f*PER+i0]; mper += v.x*c.x - v.y*c.y; }
    BTm[(size_t)t*KP + tau] = __float2bfloat16(0.3f*ml[tau] + 0.7f*mper);
  }
  for (int j=tid;j<KP-SEQ;j+=256){
    float v = 0.f;
    if (j < KW){ int p=j/FRQ, f=j-p*FRQ; v = 0.7f * sV[f*PIN+p].x; }
    BTm[(size_t)t*KP + SEQ + j] = __float2bfloat16(v);
  }
}

// ---------------- R1: x[b][t][n] -> Abig[b*128+n][t] (bf16, 64x64 tiles, short4 stores)
__global__ __launch_bounds__(256) void r1_x(const float* __restrict__ x, __hip_bfloat16* __restrict__ Abig){
  __shared__ float tile[64][65];
  int b = blockIdx.z; int t0=blockIdx.y*64; int n0=blockIdx.x*64;
  int tid=threadIdx.x;
  int c = tid & 63, r0 = tid >> 6;
  #pragma unroll
  for (int s=0;s<16;++s){
    int r = r0 + s*4;
    int t = t0 + r;
    tile[r][c] = (t<SEQ) ? x[((size_t)b*SEQ + t)*NCH + n0 + c] : 0.f;
  }
  __syncthreads();
  int nn0 = tid >> 4;
  int tq  = tid & 15;
  int tt  = t0 + tq*4;
  #pragma unroll
  for (int s=0;s<4;++s){
    int nn = nn0 + s*16;
    short4 v;
    v.x = b2s(tile[tq*4+0][nn]);
    v.y = b2s(tile[tq*4+1][nn]);
    v.z = b2s(tile[tq*4+2][nn]);
    v.w = b2s(tile[tq*4+3][nn]);
    __hip_bfloat16* dst = Abig + (size_t)(b*NCH + n0+nn)*KP + tt;
    if (tt+3 < SEQ){
      *reinterpret_cast<short4*>(dst) = v;
    } else {
      short sv[4] = {v.x, v.y, v.z, v.w};
      for (int j=0;j<4;++j) if (tt+j < SEQ) *reinterpret_cast<short*>(dst+j) = sv[j];
    }
  }
}

// ---------------- R2: Wpos rows -> Abig cols [720,1728), vectorized
__global__ __launch_bounds__(256) void r2_wpos(const float* __restrict__ Wp, __hip_bfloat16* __restrict__ Abig){
  int bn = blockIdx.x; int tid=threadIdx.x;
  int j = tid*4;
  if (j >= KP-SEQ) return;
  const float* src = Wp + (size_t)bn*KW;
  float f0,f1,f2,f3;
  if (j+3 < KW){
    float2 u = *reinterpret_cast<const float2*>(src+j);
    float2 w = *reinterpret_cast<const float2*>(src+j+2);
    f0=u.x; f1=u.y; f2=w.x; f3=w.y;
  } else {
    f0=(j  <KW)?src[j  ]:0.f; f1=(j+1<KW)?src[j+1]:0.f;
    f2=(j+2<KW)?src[j+2]:0.f; f3=(j+3<KW)?src[j+3]:0.f;
  }
  short4 v = { b2s(f0), b2s(f1), b2s(f2), b2s(f3) };
  *reinterpret_cast<short4*>(Abig + (size_t)bn*KP + SEQ + j) = v;
}

// ---------------- GEMM (BK=64, XCD swizzle): out[b,t,n] = sum_k BT[t,k]*Abig[bn,k] + bias[t]
typedef __attribute__((ext_vector_type(8))) short bfrag_t;
typedef __attribute__((ext_vector_type(4))) float accf_t;
typedef __attribute__((address_space(1))) void gvoid;
typedef __attribute__((address_space(3))) void lvoid;

__device__ __forceinline__ void gload16(const void* g, void* l){
  __builtin_amdgcn_global_load_lds((gvoid*)(g), (lvoid*)(l), 16, 0, 0);
}

__global__ __launch_bounds__(256) void gemm_main(const __hip_bfloat16* __restrict__ BTm,
                                                 const __hip_bfloat16* __restrict__ Abig,
                                                 const float* __restrict__ bias,
                                                 float* __restrict__ out)
{
  __shared__ __hip_bfloat16 At[128*64];
  __shared__ __hip_bfloat16 Bt[128*64];
  int tid = threadIdx.x;
  int lane = tid & 63;
  int wv = tid >> 6;
  int wr = wv >> 1, wc = wv & 1;
  // XCD-aware bijective swizzle: 768 blocks, 8 XCDs, 96 per XCD
  int flat = blockIdx.y*128 + blockIdx.x;
  int swz = (flat & 7)*96 + (flat >> 3);
  int t0 = (swz >> 7)*128, bn0 = (swz & 127)*128;

  accf_t acc[4][4];
  #pragma unroll
  for (int i=0;i<4;++i)
    #pragma unroll
    for (int j=0;j<4;++j) acc[i][j] = (accf_t){0.f,0.f,0.f,0.f};

  // staging: tile = 128 rows x 64 k (128B rows, 8 x 16B units); 1024 units, 4 per thread
  // LDS linear (gload_lds constraint); source k-unit pre-swizzled: us = u ^ (row&7)
  const __hip_bfloat16* gA[4];
  const __hip_bfloat16* gB[4];
  char* lA[4]; char* lB[4];
  #pragma unroll
  for (int i=0;i<4;++i){
    int lin = i*256 + tid;
    int row = lin >> 3, u = lin & 7;
    int us = u ^ (row & 7);
    gA[i] = BTm  + (size_t)(t0 + row)*KP + us*8;
    gB[i] = Abig + (size_t)(bn0+ row)*KP + us*8;
    lA[i] = (char*)At + lin*16;
    lB[i] = (char*)Bt + lin*16;
  }

  int g = lane >> 4;
  int arow = wr*64 + (lane & 15);
  int brow = wc*64 + (lane & 15);

  for (int ks=0; ks<KP/64; ++ks){
    int k0 = ks*64;
    #pragma unroll
    for (int i=0;i<4;++i) gload16(gA[i] + k0, lA[i]);
    #pragma unroll
    for (int i=0;i<4;++i) gload16(gB[i] + k0, lB[i]);
    __syncthreads();   // drains vmcnt before ds_read
    #pragma unroll
    for (int kh=0; kh<2; ++kh){
      bfrag_t af[4], bb[4];
      #pragma unroll
      for (int mi=0;mi<4;++mi){
        int r = arow + mi*16;
        int q = (kh*4 + g) ^ (r & 7);
        af[mi] = *(const bfrag_t*)((const char*)At + r*128 + q*16);
      }
      #pragma unroll
      for (int ni=0;ni<4;++ni){
        int r = brow + ni*16;
        int q = (kh*4 + g) ^ (r & 7);
        bb[ni] = *(const bfrag_t*)((const char*)Bt + r*128 + q*16);
      }
      #pragma unroll
      for (int mi=0;mi<4;++mi)
        #pragma unroll
        for (int ni=0;ni<4;++ni)
          acc[mi][ni] = __builtin_amdgcn_mfma_f32_16x16x32_bf16(af[mi], bb[ni], acc[mi][ni], 0, 0, 0);
    }
    __syncthreads();   // compute done before next stage overwrites
  }

  #pragma unroll
  for (int mi=0;mi<4;++mi){
    int tbase = t0 + wr*64 + mi*16 + (lane>>4)*4;
    #pragma unroll
    for (int ni=0;ni<4;++ni){
      int col = bn0 + wc*64 + ni*16 + (lane&15);
      int b = col>>7, n = col&127;
      size_t obase = (size_t)b*(SEQ*NCH) + n;
      #pragma unroll
      for (int r=0;r<4;++r){
        int t = tbase + r;
        if (t<SEQ) out[obase + (size_t)t*NCH] = acc[mi][ni][r] + bias[t];
      }
    }
  }
}

extern "C" void kernel_launch(void* const* d_in, const int* in_sizes, int n_in,
                              void* d_out, int out_size, void* d_ws, size_t ws_size,
                              hipStream_t stream)
{
  const float* x     = (const float*)d_in[0];
  const float* fqWr  = (const float*)d_in[1];
  const float* fqWi  = (const float*)d_in[2];
  const float* fqbr  = (const float*)d_in[3];
  const float* fqbi  = (const float*)d_in[4];
  const float* WPW   = (const float*)d_in[5];
  const float* WPb   = (const float*)d_in[6];
  const float* Wpos  = (const float*)d_in[7];
  const float* m1r   = (const float*)d_in[8];
  const float* m1i   = (const float*)d_in[9];
  const float* m1br  = (const float*)d_in[10];
  const float* m1bi  = (const float*)d_in[11];
  const float* fxr   = (const float*)d_in[12];
  const float* fxi   = (const float*)d_in[13];
  const float* fxbr  = (const float*)d_in[14];
  const float* fxbi  = (const float*)d_in[15];
  const float* pjr   = (const float*)d_in[16];
  const float* pji   = (const float*)d_in[17];
  const float* pjbr  = (const float*)d_in[18];
  const float* pjbi  = (const float*)d_in[19];
  const float* headW = (const float*)d_in[20];
  const float* headb = (const float*)d_in[21];

  char* ws = (char*)d_ws;
  size_t off = 0;
  auto alloc = [&](size_t bytes)->void*{ void* p = ws + off; off += (bytes + 255) & ~(size_t)255; return p; };
  __hip_bfloat16* Abig = (__hip_bfloat16*)alloc((size_t)BN*KP*2);
  __hip_bfloat16* BTm  = (__hip_bfloat16*)alloc((size_t)MT*KP*2);
  cf* V    = (cf*)alloc((size_t)SEQ*990*8);
  float* A1r = (float*)alloc((size_t)DOM*720*4);
  float* A1i = (float*)alloc((size_t)DOM*720*4);
  float* Mlow= (float*)alloc((size_t)SEQ*720*4);
  cf* C   = (cf*)alloc((size_t)FRQ*PER*8);
  cf* PM  = (cf*)alloc((size_t)POUT*PIN*8);
  cf* M2  = (cf*)alloc((size_t)FRQ*FRQ*8);
  cf* o3b = (cf*)alloc((size_t)FRQ*POUT*8);
  float* bias = (float*)alloc((size_t)SEQ*4);

  p15<<<DOM+1,256,0,stream>>>(WPW,WPb, m1r,m1i,m1br,m1bi, fxr,fxi,fxbr,fxbi, pjr,pji,pjbr,pjbi,
                              fqWr,fqWi, C,PM,M2,o3b, A1r,A1i);
  p5m_mlow<<<dim3(45,45),256,0,stream>>>(A1r, A1i, Mlow);
  p_big<<<SEQ,256,0,stream>>>(headW, PM, M2, o3b, fqbr, fqbi, headb, V, bias);
  p6_bt<<<SEQ,256,0,stream>>>(V, C, Mlow, BTm);
  r1_x<<<dim3(2,12,BATCH), 256, 0, stream>>>(x, Abig);
  r2_wpos<<<BN,256,0,stream>>>(Wpos, Abig);
  gemm_main<<<dim3(128, 6), 256, 0, stream>>>(BTm, Abig, bias, (float*)d_out);
}

// Round 10
// 205.854 us; speedup vs baseline: 1.0049x; 1.0049x over previous
//
#include <hip/hip_runtime.h>
#include <hip/hip_bf16.h>
#include <math.h>

#define SEQ 720
#define NCH 128
#define BATCH 128
#define BN 16384
#define DOM 72
#define PIN 30
#define POUT 30
#define FRQ 33
#define EMB 64
#define PER 24
#define KW 990
#define KP 1728
#define MT 768
#define PI_F 3.14159265358979323846f

typedef float2 cf;
__device__ __forceinline__ cf cmac(cf acc, cf a, cf b){
  acc.x += a.x*b.x - a.y*b.y; acc.y += a.x*b.y + a.y*b.x; return acc;
}
__device__ __forceinline__ short b2s(float f){
  __hip_bfloat16 h = __float2bfloat16(f);
  return *reinterpret_cast<short*>(&h);
}

// ---------------- P15: block 72 = p1 weight-composition; blocks 0..71 = p5 A1 rows ----------------
__global__ __launch_bounds__(256) void p15(const float* __restrict__ WPW, const float* __restrict__ WPb,
                         const float* __restrict__ m1r, const float* __restrict__ m1i,
                         const float* __restrict__ m1br, const float* __restrict__ m1bi,
                         const float* __restrict__ fxr, const float* __restrict__ fxi,
                         const float* __restrict__ fxbr, const float* __restrict__ fxbi,
                         const float* __restrict__ pjr, const float* __restrict__ pji,
                         const float* __restrict__ pjbr, const float* __restrict__ pjbi,
                         const float* __restrict__ fqr, const float* __restrict__ fqi,
                         cf* C, cf* PM, cf* M2, cf* o3b,
                         float* __restrict__ A1r, float* __restrict__ A1i)
{
  // p1 LDS
  __shared__ cf e64[64];
  __shared__ float sW[EMB*PER];
  __shared__ float sWb[EMB];
  __shared__ float sM1r[PIN*PIN], sM1i[PIN*PIN];
  __shared__ float sFxr[FRQ*FRQ], sFxi[FRQ*FRQ];
  __shared__ float sPjr[POUT*PIN], sPji[POUT*PIN];
  __shared__ float sB[6*33];
  __shared__ cf s_d[FRQ];
  __shared__ cf s_rs[PIN];
  __shared__ cf s_o1[FRQ*PIN];
  __shared__ cf s_o2[FRQ*PIN];
  // p5 LDS
  __shared__ cf tbl[720];
  __shared__ cf wrow[DOM];

  int tid = threadIdx.x;
  if (blockIdx.x < DOM){
    // ---- p5 path: A1[k][tau] ----
    int k = blockIdx.x;
    for (int m=tid;m<720;m+=256){ float s,c; sincosf(-2.f*PI_F*(float)m/720.f,&s,&c); tbl[m]=make_float2(c,s); }
    for (int j=tid;j<DOM;j+=256) wrow[j]=make_float2(fqr[k*DOM+j], fqi[k*DOM+j]);
    __syncthreads();
    for (int tau=tid; tau<720; tau+=256){
      cf acc=make_float2(0.f,0.f);
      for (int j=0;j<DOM;++j) acc = cmac(acc, wrow[j], tbl[(j*tau)%720]);
      A1r[k*720+tau]=acc.x;
      A1i[k*720+tau]=acc.y;
    }
    return;
  }
  // ---- p1 path ----
  if (tid < 64){ float s,c; sincosf(2.f*PI_F*tid/64.f, &s, &c); e64[tid] = make_float2(c, s); }
  for (int i=tid; i<EMB*PER; i+=256) sW[i]=WPW[i];
  if (tid < EMB) sWb[tid]=WPb[tid];
  for (int i=tid; i<PIN*PIN; i+=256){ sM1r[i]=m1r[i]; sM1i[i]=m1i[i]; sPjr[i]=pjr[i]; sPji[i]=pji[i]; }
  for (int i=tid; i<FRQ*FRQ; i+=256){ sFxr[i]=fxr[i]; sFxi[i]=fxi[i]; }
  if (tid < PIN)  { sB[tid]      = m1br[tid]; sB[33+tid]  = m1bi[tid]; }
  if (tid < FRQ)  { sB[66+tid]   = fxbr[tid]; sB[99+tid]  = fxbi[tid]; }
  if (tid < POUT) { sB[132+tid]  = pjbr[tid]; sB[165+tid] = pjbi[tid]; }
  __syncthreads();
  for (int idx=tid; idx<FRQ*PER; idx+=256){
    int f = idx/PER, i = idx%PER;
    cf acc = make_float2(0.f,0.f);
    #pragma unroll 8
    for (int o=0;o<EMB;++o){ cf e = e64[(f*o)&63]; float w = sW[o*PER+i]; acc.x += w*e.x; acc.y -= w*e.y; }
    C[idx] = acc;
  }
  for (int f=tid; f<FRQ; f+=256){
    cf acc = make_float2(0.f,0.f);
    #pragma unroll 8
    for (int o=0;o<EMB;++o){ cf e = e64[(f*o)&63]; acc.x += sWb[o]*e.x; acc.y -= sWb[o]*e.y; }
    s_d[f]=acc;
  }
  for (int idx=tid; idx<POUT*PIN; idx+=256){
    int q = idx/PIN, pp = idx%PIN;
    cf acc = make_float2(sPjr[q*PIN+pp], sPji[q*PIN+pp]);
    #pragma unroll 6
    for (int p=0;p<PIN;++p){
      cf a = make_float2(sPjr[q*PIN+p], sPji[q*PIN+p]);
      cf b = make_float2(sM1r[p*PIN+pp], sM1i[p*PIN+pp]);
      acc = cmac(acc, a, b);
    }
    PM[idx]=acc;
  }
  for (int idx=tid; idx<FRQ*FRQ; idx+=256){
    int f = idx/FRQ, ff = idx%FRQ;
    cf v = make_float2(sFxr[idx], sFxi[idx]); if (f==ff) v.x += 1.f;
    M2[idx]=v;
  }
  for (int p=tid; p<PIN; p+=256){
    cf acc = make_float2(1.f,0.f);
    #pragma unroll 6
    for (int pp=0;pp<PIN;++pp){ acc.x += sM1r[p*PIN+pp]; acc.y += sM1i[p*PIN+pp]; }
    s_rs[p]=acc;
  }
  __syncthreads();
  for (int idx=tid; idx<FRQ*PIN; idx+=256){
    int f = idx/PIN, p = idx%PIN;
    cf v = make_float2(0.f,0.f); v = cmac(v, s_d[f], s_rs[p]);
    v.x += sB[p]; v.y += sB[33+p];
    s_o1[idx]=v;
  }
  __syncthreads();
  for (int idx=tid; idx<FRQ*PIN; idx+=256){
    int f = idx/PIN, p = idx%PIN;
    cf acc = make_float2(sB[66+f], sB[99+f]);
    #pragma unroll 4
    for (int ff=0; ff<FRQ; ++ff){
      cf m2 = make_float2(sFxr[f*FRQ+ff], sFxi[f*FRQ+ff]); if (f==ff) m2.x += 1.f;
      acc = cmac(acc, m2, s_o1[ff*PIN+p]);
    }
    s_o2[idx]=acc;
  }
  __syncthreads();
  for (int idx=tid; idx<FRQ*POUT; idx+=256){
    int f = idx/POUT, q = idx%POUT;
    cf acc = make_float2(sB[132+q], sB[165+q]);
    #pragma unroll 6
    for (int p=0;p<PIN;++p){
      cf a = make_float2(sPjr[q*PIN+p], sPji[q*PIN+p]);
      acc = cmac(acc, a, s_o2[f*PIN+p]);
    }
    o3b[f*POUT+q]=acc;
  }
}

// ---------------- P5M: Mlow[t][tau] = sum_k Gr[t,k]A1r[k,tau] - Gi[t,k]A1i[k,tau]
__global__ __launch_bounds__(256) void p5m_mlow(const float* __restrict__ A1r,
                                                const float* __restrict__ A1i,
                                                float* __restrict__ Mlow){
  __shared__ float sG[16*144];
  __shared__ float sA[144*16];
  int t0 = blockIdx.y*16, tau0 = blockIdx.x*16;
  int tid = threadIdx.x;
  for (int i=tid; i<16*72; i+=256){
    int tt=i/72, k=i%72;
    int m = ((t0+tt)*k) % 720;
    float s,c; sincosf(2.f*PI_F*(float)m/720.f,&s,&c);
    float sc = (k==0)?(1.f/720.f):(2.f/720.f);
    sG[tt*144+k]    = c*sc;
    sG[tt*144+72+k] = s*sc;
  }
  for (int i=tid; i<72*16; i+=256){
    int k=i/16, tc=i%16;
    sA[k*16+tc]      = A1r[k*720+tau0+tc];
    sA[(72+k)*16+tc] = A1i[k*720+tau0+tc];
  }
  __syncthreads();
  int tt=tid/16, tc=tid%16;
  float acc=0.f;
  #pragma unroll 8
  for (int k=0;k<72;++k)
    acc += sG[tt*144+k]*sA[k*16+tc] - sG[tt*144+72+k]*sA[(72+k)*16+tc];
  Mlow[(size_t)(t0+tt)*720 + tau0+tc] = acc;
}

// ---------------- P_BIG: per-t merged p2+p3+p4+p7 -> V[t], bias[t] ----------------
__global__ __launch_bounds__(256) void p_big(const float* __restrict__ hW,
                    const cf* __restrict__ PM, const cf* __restrict__ M2, const cf* __restrict__ o3b,
                    const float* __restrict__ fbr, const float* __restrict__ fbi,
                    const float* __restrict__ headb,
                    cf* __restrict__ V, float* __restrict__ bias){
  __shared__ cf e64[64];
  __shared__ float shw[1920];
  __shared__ cf sHc[990];
  __shared__ cf sV1[990];
  __shared__ cf sPM[POUT*PIN];
  __shared__ cf sM2[FRQ*FRQ];
  __shared__ cf sO3[FRQ*POUT];
  __shared__ float red[256];
  int tid=threadIdx.x; int t=blockIdx.x;
  if (tid<64){ float s,c; sincosf(2.f*PI_F*tid/64.f,&s,&c); e64[tid]=make_float2(c,s); }
  for (int i=tid;i<1920;i+=256) shw[i]=hW[(size_t)t*1920+i];
  for (int i=tid;i<POUT*PIN;i+=256) sPM[i]=PM[i];
  for (int i=tid;i<FRQ*FRQ;i+=256) sM2[i]=M2[i];
  for (int i=tid;i<FRQ*POUT;i+=256) sO3[i]=o3b[i];
  __syncthreads();
  for (int idx=tid; idx<990; idx+=256){
    int q=idx/FRQ, f=idx%FRQ;
    cf acc=make_float2(0.f,0.f);
    const float* hw = &shw[q*64];
    for (int o=0;o<EMB;++o){ cf e=e64[(f*o)&63]; float w=hw[o]; acc.x+=w*e.x; acc.y+=w*e.y; }
    float s=((f==0)||(f==32))?(1.f/64.f):(2.f/64.f);
    sHc[idx]=make_float2(acc.x*s, acc.y*s);
  }
  __syncthreads();
  for (int idx=tid; idx<990; idx+=256){
    int f=idx/PIN, p=idx%PIN;
    cf acc=make_float2(0.f,0.f);
    for (int q=0;q<POUT;++q) acc=cmac(acc, sHc[q*FRQ+f], sPM[q*PIN+p]);
    sV1[idx]=acc;
  }
  __syncthreads();
  for (int idx=tid; idx<990; idx+=256){
    int ff=idx/PIN, pp=idx%PIN;
    cf acc=make_float2(0.f,0.f);
    for (int f=0;f<FRQ;++f) acc=cmac(acc, sV1[f*PIN+pp], sM2[f*FRQ+ff]);
    V[(size_t)t*990+idx]=acc;
  }
  float part=0.f;
  for (int idx=tid; idx<990; idx+=256){
    int q=idx/FRQ, f=idx%FRQ;
    cf h=sHc[idx]; cf o=sO3[f*POUT+q];
    part += h.x*o.x - h.y*o.y;
  }
  part *= 0.7f;
  if (tid<DOM){
    int m=(tid*t)%720; float s,c; sincosf(2.f*PI_F*(float)m/720.f,&s,&c);
    float sc=(tid==0)?(1.f/720.f):(2.f/720.f);
    part += 0.3f*sc*(c*fbr[tid] - s*fbi[tid]);
  }
  red[tid]=part; __syncthreads();
  for (int s=128;s>0;s>>=1){ if (tid<s) red[tid]+=red[tid+s]; __syncthreads(); }
  if (tid==0) bias[t] = red[0] + 0.7f*headb[t];
}

// ---------------- P6: build fused bf16 weight row t ----------------
__global__ void p6_bt(const cf* __restrict__ V, const cf* __restrict__ C,
                      const float* __restrict__ Mlow, __hip_bfloat16* __restrict__ BTm){
  __shared__ cf sV[990];
  __shared__ cf sC[FRQ*PER];
  int tid=threadIdx.x; int t=blockIdx.x;
  for (int i=tid;i<990;i+=256) sV[i]=V[(size_t)t*990+i];
  for (int i=tid;i<FRQ*PER;i+=256) sC[i]=C[i];
  __syncthreads();
  const float* ml = Mlow + (size_t)t*720;
  for (int tau=tid; tau<720; tau+=256){
    int p0 = tau/PER, i0 = tau - p0*PER;
    float mper=0.f;
    for (int f=0; f<FRQ; ++f){ cf v=sV[f*PIN+p0]; cf c=sC[f*PER+i0]; mper += v.x*c.x - v.y*c.y; }
    BTm[(size_t)t*KP + tau] = __float2bfloat16(0.3f*ml[tau] + 0.7f*mper);
  }
  for (int j=tid;j<KP-SEQ;j+=256){
    float v = 0.f;
    if (j < KW){ int p=j/FRQ, f=j-p*FRQ; v = 0.7f * sV[f*PIN+p].x; }
    BTm[(size_t)t*KP + SEQ + j] = __float2bfloat16(v);
  }
}

// ---------------- R1: x[b][t][n] -> Abig[b*128+n][t] (bf16, 64x64 tiles, short4 stores)
__global__ __launch_bounds__(256) void r1_x(const float* __restrict__ x, __hip_bfloat16* __restrict__ Abig){
  __shared__ float tile[64][65];
  int b = blockIdx.z; int t0=blockIdx.y*64; int n0=blockIdx.x*64;
  int tid=threadIdx.x;
  int c = tid & 63, r0 = tid >> 6;
  #pragma unroll
  for (int s=0;s<16;++s){
    int r = r0 + s*4;
    int t = t0 + r;
    tile[r][c] = (t<SEQ) ? x[((size_t)b*SEQ + t)*NCH + n0 + c] : 0.f;
  }
  __syncthreads();
  int nn0 = tid >> 4;
  int tq  = tid & 15;
  int tt  = t0 + tq*4;
  #pragma unroll
  for (int s=0;s<4;++s){
    int nn = nn0 + s*16;
    short4 v;
    v.x = b2s(tile[tq*4+0][nn]);
    v.y = b2s(tile[tq*4+1][nn]);
    v.z = b2s(tile[tq*4+2][nn]);
    v.w = b2s(tile[tq*4+3][nn]);
    __hip_bfloat16* dst = Abig + (size_t)(b*NCH + n0+nn)*KP + tt;
    if (tt+3 < SEQ){
      *reinterpret_cast<short4*>(dst) = v;
    } else {
      short sv[4] = {v.x, v.y, v.z, v.w};
      for (int j=0;j<4;++j) if (tt+j < SEQ) *reinterpret_cast<short*>(dst+j) = sv[j];
    }
  }
}

// ---------------- R2: Wpos rows -> Abig cols [720,1728), vectorized
__global__ __launch_bounds__(256) void r2_wpos(const float* __restrict__ Wp, __hip_bfloat16* __restrict__ Abig){
  int bn = blockIdx.x; int tid=threadIdx.x;
  int j = tid*4;
  if (j >= KP-SEQ) return;
  const float* src = Wp + (size_t)bn*KW;
  float f0,f1,f2,f3;
  if (j+3 < KW){
    float2 u = *reinterpret_cast<const float2*>(src+j);
    float2 w = *reinterpret_cast<const float2*>(src+j+2);
    f0=u.x; f1=u.y; f2=w.x; f3=w.y;
  } else {
    f0=(j  <KW)?src[j  ]:0.f; f1=(j+1<KW)?src[j+1]:0.f;
    f2=(j+2<KW)?src[j+2]:0.f; f3=(j+3<KW)?src[j+3]:0.f;
  }
  short4 v = { b2s(f0), b2s(f1), b2s(f2), b2s(f3) };
  *reinterpret_cast<short4*>(Abig + (size_t)bn*KP + SEQ + j) = v;
}

// ---------------- GEMM (BK=64, natural tile mapping): out[b,t,n] = sum_k BT[t,k]*Abig[bn,k] + bias[t]
typedef __attribute__((ext_vector_type(8))) short bfrag_t;
typedef __attribute__((ext_vector_type(4))) float accf_t;
typedef __attribute__((address_space(1))) void gvoid;
typedef __attribute__((address_space(3))) void lvoid;

__device__ __forceinline__ void gload16(const void* g, void* l){
  __builtin_amdgcn_global_load_lds((gvoid*)(g), (lvoid*)(l), 16, 0, 0);
}

__global__ __launch_bounds__(256) void gemm_main(const __hip_bfloat16* __restrict__ BTm,
                                                 const __hip_bfloat16* __restrict__ Abig,
                                                 const float* __restrict__ bias,
                                                 float* __restrict__ out)
{
  __shared__ __hip_bfloat16 At[128*64];
  __shared__ __hip_bfloat16 Bt[128*64];
  int tid = threadIdx.x;
  int lane = tid & 63;
  int wv = tid >> 6;
  int wr = wv >> 1, wc = wv & 1;
  // NATURAL mapping: flat = t_tile*128 + bn_tile. 128 ≡ 0 (mod 8) means the 6 blocks
  // sharing one Abig panel (same bn, t=0..5) land on the SAME XCD under HW round-robin
  // -> panel fetched once per L2. (Round-9's remap broke this: FETCH 38->170 MB.)
  int t0 = blockIdx.y*128, bn0 = blockIdx.x*128;

  accf_t acc[4][4];
  #pragma unroll
  for (int i=0;i<4;++i)
    #pragma unroll
    for (int j=0;j<4;++j) acc[i][j] = (accf_t){0.f,0.f,0.f,0.f};

  // staging: tile = 128 rows x 64 k (128B rows, 8 x 16B units); 1024 units, 4 per thread
  // LDS linear (gload_lds constraint); source k-unit pre-swizzled: us = u ^ (row&7)
  const __hip_bfloat16* gA[4];
  const __hip_bfloat16* gB[4];
  char* lA[4]; char* lB[4];
  #pragma unroll
  for (int i=0;i<4;++i){
    int lin = i*256 + tid;
    int row = lin >> 3, u = lin & 7;
    int us = u ^ (row & 7);
    gA[i] = BTm  + (size_t)(t0 + row)*KP + us*8;
    gB[i] = Abig + (size_t)(bn0+ row)*KP + us*8;
    lA[i] = (char*)At + lin*16;
    lB[i] = (char*)Bt + lin*16;
  }

  int g = lane >> 4;
  int arow = wr*64 + (lane & 15);
  int brow = wc*64 + (lane & 15);

  for (int ks=0; ks<KP/64; ++ks){
    int k0 = ks*64;
    #pragma unroll
    for (int i=0;i<4;++i) gload16(gA[i] + k0, lA[i]);
    #pragma unroll
    for (int i=0;i<4;++i) gload16(gB[i] + k0, lB[i]);
    __syncthreads();   // drains vmcnt before ds_read
    #pragma unroll
    for (int kh=0; kh<2; ++kh){
      bfrag_t af[4], bb[4];
      #pragma unroll
      for (int mi=0;mi<4;++mi){
        int r = arow + mi*16;
        int q = (kh*4 + g) ^ (r & 7);
        af[mi] = *(const bfrag_t*)((const char*)At + r*128 + q*16);
      }
      #pragma unroll
      for (int ni=0;ni<4;++ni){
        int r = brow + ni*16;
        int q = (kh*4 + g) ^ (r & 7);
        bb[ni] = *(const bfrag_t*)((const char*)Bt + r*128 + q*16);
      }
      #pragma unroll
      for (int mi=0;mi<4;++mi)
        #pragma unroll
        for (int ni=0;ni<4;++ni)
          acc[mi][ni] = __builtin_amdgcn_mfma_f32_16x16x32_bf16(af[mi], bb[ni], acc[mi][ni], 0, 0, 0);
    }
    __syncthreads();   // compute done before next stage overwrites
  }

  #pragma unroll
  for (int mi=0;mi<4;++mi){
    int tbase = t0 + wr*64 + mi*16 + (lane>>4)*4;
    #pragma unroll
    for (int ni=0;ni<4;++ni){
      int col = bn0 + wc*64 + ni*16 + (lane&15);
      int b = col>>7, n = col&127;
      size_t obase = (size_t)b*(SEQ*NCH) + n;
      #pragma unroll
      for (int r=0;r<4;++r){
        int t = tbase + r;
        if (t<SEQ) out[obase + (size_t)t*NCH] = acc[mi][ni][r] + bias[t];
      }
    }
  }
}

extern "C" void kernel_launch(void* const* d_in, const int* in_sizes, int n_in,
                              void* d_out, int out_size, void* d_ws, size_t ws_size,
                              hipStream_t stream)
{
  const float* x     = (const float*)d_in[0];
  const float* fqWr  = (const float*)d_in[1];
  const float* fqWi  = (const float*)d_in[2];
  const float* fqbr  = (const float*)d_in[3];
  const float* fqbi  = (const float*)d_in[4];
  const float* WPW   = (const float*)d_in[5];
  const float* WPb   = (const float*)d_in[6];
  const float* Wpos  = (const float*)d_in[7];
  const float* m1r   = (const float*)d_in[8];
  const float* m1i   = (const float*)d_in[9];
  const float* m1br  = (const float*)d_in[10];
  const float* m1bi  = (const float*)d_in[11];
  const float* fxr   = (const float*)d_in[12];
  const float* fxi   = (const float*)d_in[13];
  const float* fxbr  = (const float*)d_in[14];
  const float* fxbi  = (const float*)d_in[15];
  const float* pjr   = (const float*)d_in[16];
  const float* pji   = (const float*)d_in[17];
  const float* pjbr  = (const float*)d_in[18];
  const float* pjbi  = (const float*)d_in[19];
  const float* headW = (const float*)d_in[20];
  const float* headb = (const float*)d_in[21];

  char* ws = (char*)d_ws;
  size_t off = 0;
  auto alloc = [&](size_t bytes)->void*{ void* p = ws + off; off += (bytes + 255) & ~(size_t)255; return p; };
  __hip_bfloat16* Abig = (__hip_bfloat16*)alloc((size_t)BN*KP*2);
  __hip_bfloat16* BTm  = (__hip_bfloat16*)alloc((size_t)MT*KP*2);
  cf* V    = (cf*)alloc((size_t)SEQ*990*8);
  float* A1r = (float*)alloc((size_t)DOM*720*4);
  float* A1i = (float*)alloc((size_t)DOM*720*4);
  float* Mlow= (float*)alloc((size_t)SEQ*720*4);
  cf* C   = (cf*)alloc((size_t)FRQ*PER*8);
  cf* PM  = (cf*)alloc((size_t)POUT*PIN*8);
  cf* M2  = (cf*)alloc((size_t)FRQ*FRQ*8);
  cf* o3b = (cf*)alloc((size_t)FRQ*POUT*8);
  float* bias = (float*)alloc((size_t)SEQ*4);

  p15<<<DOM+1,256,0,stream>>>(WPW,WPb, m1r,m1i,m1br,m1bi, fxr,fxi,fxbr,fxbi, pjr,pji,pjbr,pjbi,
                              fqWr,fqWi, C,PM,M2,o3b, A1r,A1i);
  p5m_mlow<<<dim3(45,45),256,0,stream>>>(A1r, A1i, Mlow);
  p_big<<<SEQ,256,0,stream>>>(headW, PM, M2, o3b, fqbr, fqbi, headb, V, bias);
  p6_bt<<<SEQ,256,0,stream>>>(V, C, Mlow, BTm);
  r1_x<<<dim3(2,12,BATCH), 256, 0, stream>>>(x, Abig);
  r2_wpos<<<BN,256,0,stream>>>(Wpos, Abig);
  gemm_main<<<dim3(128, 6), 256, 0, stream>>>(BTm, Abig, bias, (float*)d_out);
}

// Round 11
// 175.562 us; speedup vs baseline: 1.1783x; 1.1725x over previous
//
#include <hip/hip_runtime.h>
#include <hip/hip_bf16.h>
#include <math.h>

#define SEQ 720
#define NCH 128
#define BATCH 128
#define BN 16384
#define DOM 72
#define PIN 30
#define POUT 30
#define FRQ 33
#define EMB 64
#define PER 24
#define KW 990
#define KP 1728
#define MT 768
#define PI_F 3.14159265358979323846f

typedef float2 cf;
__device__ __forceinline__ cf cmac(cf acc, cf a, cf b){
  acc.x += a.x*b.x - a.y*b.y; acc.y += a.x*b.y + a.y*b.x; return acc;
}
__device__ __forceinline__ short b2s(float f){
  __hip_bfloat16 h = __float2bfloat16(f);
  return *reinterpret_cast<short*>(&h);
}

// ---------------- P15: block 72 = p1 weight-composition; blocks 0..71 = p5 A1 rows ----------------
__global__ __launch_bounds__(256) void p15(const float* __restrict__ WPW, const float* __restrict__ WPb,
                         const float* __restrict__ m1r, const float* __restrict__ m1i,
                         const float* __restrict__ m1br, const float* __restrict__ m1bi,
                         const float* __restrict__ fxr, const float* __restrict__ fxi,
                         const float* __restrict__ fxbr, const float* __restrict__ fxbi,
                         const float* __restrict__ pjr, const float* __restrict__ pji,
                         const float* __restrict__ pjbr, const float* __restrict__ pjbi,
                         const float* __restrict__ fqr, const float* __restrict__ fqi,
                         cf* C, cf* PM, cf* M2, cf* o3b,
                         float* __restrict__ A1r, float* __restrict__ A1i)
{
  __shared__ cf e64[64];
  __shared__ float sW[EMB*PER];
  __shared__ float sWb[EMB];
  __shared__ float sM1r[PIN*PIN], sM1i[PIN*PIN];
  __shared__ float sFxr[FRQ*FRQ], sFxi[FRQ*FRQ];
  __shared__ float sPjr[POUT*PIN], sPji[POUT*PIN];
  __shared__ float sB[6*33];
  __shared__ cf s_d[FRQ];
  __shared__ cf s_rs[PIN];
  __shared__ cf s_o1[FRQ*PIN];
  __shared__ cf s_o2[FRQ*PIN];
  __shared__ cf tbl[720];
  __shared__ cf wrow[DOM];

  int tid = threadIdx.x;
  if (blockIdx.x < DOM){
    int k = blockIdx.x;
    for (int m=tid;m<720;m+=256){ float s,c; sincosf(-2.f*PI_F*(float)m/720.f,&s,&c); tbl[m]=make_float2(c,s); }
    for (int j=tid;j<DOM;j+=256) wrow[j]=make_float2(fqr[k*DOM+j], fqi[k*DOM+j]);
    __syncthreads();
    for (int tau=tid; tau<720; tau+=256){
      cf acc=make_float2(0.f,0.f);
      for (int j=0;j<DOM;++j) acc = cmac(acc, wrow[j], tbl[(j*tau)%720]);
      A1r[k*720+tau]=acc.x;
      A1i[k*720+tau]=acc.y;
    }
    return;
  }
  if (tid < 64){ float s,c; sincosf(2.f*PI_F*tid/64.f, &s, &c); e64[tid] = make_float2(c, s); }
  for (int i=tid; i<EMB*PER; i+=256) sW[i]=WPW[i];
  if (tid < EMB) sWb[tid]=WPb[tid];
  for (int i=tid; i<PIN*PIN; i+=256){ sM1r[i]=m1r[i]; sM1i[i]=m1i[i]; sPjr[i]=pjr[i]; sPji[i]=pji[i]; }
  for (int i=tid; i<FRQ*FRQ; i+=256){ sFxr[i]=fxr[i]; sFxi[i]=fxi[i]; }
  if (tid < PIN)  { sB[tid]      = m1br[tid]; sB[33+tid]  = m1bi[tid]; }
  if (tid < FRQ)  { sB[66+tid]   = fxbr[tid]; sB[99+tid]  = fxbi[tid]; }
  if (tid < POUT) { sB[132+tid]  = pjbr[tid]; sB[165+tid] = pjbi[tid]; }
  __syncthreads();
  for (int idx=tid; idx<FRQ*PER; idx+=256){
    int f = idx/PER, i = idx%PER;
    cf acc = make_float2(0.f,0.f);
    #pragma unroll 8
    for (int o=0;o<EMB;++o){ cf e = e64[(f*o)&63]; float w = sW[o*PER+i]; acc.x += w*e.x; acc.y -= w*e.y; }
    C[idx] = acc;
  }
  for (int f=tid; f<FRQ; f+=256){
    cf acc = make_float2(0.f,0.f);
    #pragma unroll 8
    for (int o=0;o<EMB;++o){ cf e = e64[(f*o)&63]; acc.x += sWb[o]*e.x; acc.y -= sWb[o]*e.y; }
    s_d[f]=acc;
  }
  for (int idx=tid; idx<POUT*PIN; idx+=256){
    int q = idx/PIN, pp = idx%PIN;
    cf acc = make_float2(sPjr[q*PIN+pp], sPji[q*PIN+pp]);
    #pragma unroll 6
    for (int p=0;p<PIN;++p){
      cf a = make_float2(sPjr[q*PIN+p], sPji[q*PIN+p]);
      cf b = make_float2(sM1r[p*PIN+pp], sM1i[p*PIN+pp]);
      acc = cmac(acc, a, b);
    }
    PM[idx]=acc;
  }
  for (int idx=tid; idx<FRQ*FRQ; idx+=256){
    int f = idx/FRQ, ff = idx%FRQ;
    cf v = make_float2(sFxr[idx], sFxi[idx]); if (f==ff) v.x += 1.f;
    M2[idx]=v;
  }
  for (int p=tid; p<PIN; p+=256){
    cf acc = make_float2(1.f,0.f);
    #pragma unroll 6
    for (int pp=0;pp<PIN;++pp){ acc.x += sM1r[p*PIN+pp]; acc.y += sM1i[p*PIN+pp]; }
    s_rs[p]=acc;
  }
  __syncthreads();
  for (int idx=tid; idx<FRQ*PIN; idx+=256){
    int f = idx/PIN, p = idx%PIN;
    cf v = make_float2(0.f,0.f); v = cmac(v, s_d[f], s_rs[p]);
    v.x += sB[p]; v.y += sB[33+p];
    s_o1[idx]=v;
  }
  __syncthreads();
  for (int idx=tid; idx<FRQ*PIN; idx+=256){
    int f = idx/PIN, p = idx%PIN;
    cf acc = make_float2(sB[66+f], sB[99+f]);
    #pragma unroll 4
    for (int ff=0; ff<FRQ; ++ff){
      cf m2 = make_float2(sFxr[f*FRQ+ff], sFxi[f*FRQ+ff]); if (f==ff) m2.x += 1.f;
      acc = cmac(acc, m2, s_o1[ff*PIN+p]);
    }
    s_o2[idx]=acc;
  }
  __syncthreads();
  for (int idx=tid; idx<FRQ*POUT; idx+=256){
    int f = idx/POUT, q = idx%POUT;
    cf acc = make_float2(sB[132+q], sB[165+q]);
    #pragma unroll 6
    for (int p=0;p<PIN;++p){
      cf a = make_float2(sPjr[q*PIN+p], sPji[q*PIN+p]);
      acc = cmac(acc, a, s_o2[f*PIN+p]);
    }
    o3b[f*POUT+q]=acc;
  }
}

// ---------------- P_BIG2: per-t p2+p3+p4+p7 + p6's mper/Wpos-cols (V never leaves LDS) ----------------
// Outputs: Mper[t][tau] = 0.7*sum_f Re(V*C);  BTm[t][720+j] = bf16(0.7*V.x);  bias[t]
__global__ __launch_bounds__(256) void p_big2(const float* __restrict__ hW,
                    const cf* __restrict__ PM, const cf* __restrict__ M2, const cf* __restrict__ o3b,
                    const cf* __restrict__ Cm,
                    const float* __restrict__ fbr, const float* __restrict__ fbi,
                    const float* __restrict__ headb,
                    float* __restrict__ Mper, __hip_bfloat16* __restrict__ BTm,
                    float* __restrict__ bias){
  __shared__ cf e64[64];
  __shared__ float shw[1920];     // phase A input; later aliased by sC (792 cf = 6336B < 7680B)
  __shared__ cf sHc[990];         // phase A out; phase D overwrites as sV
  __shared__ cf sV1[990];
  __shared__ cf sPM[POUT*PIN];
  __shared__ cf sM2[FRQ*FRQ];
  __shared__ cf sO3[FRQ*POUT];
  __shared__ float red[256];
  cf* sC = (cf*)shw;
  cf* sV = sHc;
  int tid=threadIdx.x; int t=blockIdx.x;
  if (tid<64){ float s,c; sincosf(2.f*PI_F*tid/64.f,&s,&c); e64[tid]=make_float2(c,s); }
  for (int i=tid;i<1920;i+=256) shw[i]=hW[(size_t)t*1920+i];
  for (int i=tid;i<POUT*PIN;i+=256) sPM[i]=PM[i];
  for (int i=tid;i<FRQ*FRQ;i+=256) sM2[i]=M2[i];
  for (int i=tid;i<FRQ*POUT;i+=256) sO3[i]=o3b[i];
  __syncthreads();
  // A: Hc[q][f] from shw
  for (int idx=tid; idx<990; idx+=256){
    int q=idx/FRQ, f=idx%FRQ;
    cf acc=make_float2(0.f,0.f);
    const float* hw = &shw[q*64];
    for (int o=0;o<EMB;++o){ cf e=e64[(f*o)&63]; float w=hw[o]; acc.x+=w*e.x; acc.y+=w*e.y; }
    float s=((f==0)||(f==32))?(1.f/64.f):(2.f/64.f);
    sHc[idx]=make_float2(acc.x*s, acc.y*s);
  }
  __syncthreads();   // shw consumed; sHc ready
  // B: V1 from sHc ; bias partial from sHc ; load sC (overwrites shw, safe)
  for (int idx=tid; idx<990; idx+=256){
    int f=idx/PIN, p=idx%PIN;
    cf acc=make_float2(0.f,0.f);
    for (int q=0;q<POUT;++q) acc=cmac(acc, sHc[q*FRQ+f], sPM[q*PIN+p]);
    sV1[idx]=acc;
  }
  float part=0.f;
  for (int idx=tid; idx<990; idx+=256){
    int q=idx/FRQ, f=idx%FRQ;
    cf h=sHc[idx]; cf o=sO3[f*POUT+q];
    part += h.x*o.x - h.y*o.y;
  }
  part *= 0.7f;
  if (tid<DOM){
    int m=(tid*t)%720; float s,c; sincosf(2.f*PI_F*(float)m/720.f,&s,&c);
    float sc=(tid==0)?(1.f/720.f):(2.f/720.f);
    part += 0.3f*sc*(c*fbr[tid] - s*fbi[tid]);
  }
  for (int i=tid;i<FRQ*PER;i+=256) sC[i]=Cm[i];
  red[tid]=part; __syncthreads();
  for (int s=128;s>0;s>>=1){ if (tid<s) red[tid]+=red[tid+s]; __syncthreads(); }
  if (tid==0) bias[t] = red[0] + 0.7f*headb[t];
  __syncthreads();   // all sHc reads done; sC loaded
  // D: V[ff][pp] -> sV (aliases sHc)
  for (int idx=tid; idx<990; idx+=256){
    int ff=idx/PIN, pp=idx%PIN;
    cf acc=make_float2(0.f,0.f);
    for (int f=0;f<FRQ;++f) acc=cmac(acc, sV1[f*PIN+pp], sM2[f*FRQ+ff]);
    sV[idx]=acc;
  }
  __syncthreads();
  // E: mper + Wpos columns
  for (int tau=tid; tau<720; tau+=256){
    int p0 = tau/PER, i0 = tau - p0*PER;
    float mper=0.f;
    for (int f=0; f<FRQ; ++f){ cf v=sV[f*PIN+p0]; cf c=sC[f*PER+i0]; mper += v.x*c.x - v.y*c.y; }
    Mper[(size_t)t*720 + tau] = 0.7f*mper;
  }
  for (int j=tid;j<KP-SEQ;j+=256){
    float v = 0.f;
    if (j < KW){ int p=j/FRQ, f=j-p*FRQ; v = 0.7f * sV[f*PIN+p].x; }
    BTm[(size_t)t*KP + SEQ + j] = __float2bfloat16(v);
  }
}

// ---------------- P5M2: Mlow tile + join with Mper -> BTm[:,0:720] ----------------
__global__ __launch_bounds__(256) void p5m2(const float* __restrict__ A1r,
                                            const float* __restrict__ A1i,
                                            const float* __restrict__ Mper,
                                            __hip_bfloat16* __restrict__ BTm){
  __shared__ float sG[16*144];
  __shared__ float sA[144*16];
  int t0 = blockIdx.y*16, tau0 = blockIdx.x*16;
  int tid = threadIdx.x;
  for (int i=tid; i<16*72; i+=256){
    int tt=i/72, k=i%72;
    int m = ((t0+tt)*k) % 720;
    float s,c; sincosf(2.f*PI_F*(float)m/720.f,&s,&c);
    float sc = (k==0)?(1.f/720.f):(2.f/720.f);
    sG[tt*144+k]    = c*sc;
    sG[tt*144+72+k] = s*sc;
  }
  for (int i=tid; i<72*16; i+=256){
    int k=i/16, tc=i%16;
    sA[k*16+tc]      = A1r[k*720+tau0+tc];
    sA[(72+k)*16+tc] = A1i[k*720+tau0+tc];
  }
  __syncthreads();
  int tt=tid/16, tc=tid%16;
  float acc=0.f;
  #pragma unroll 8
  for (int k=0;k<72;++k)
    acc += sG[tt*144+k]*sA[k*16+tc] - sG[tt*144+72+k]*sA[(72+k)*16+tc];
  int t = t0+tt, tau = tau0+tc;
  float mp = Mper[(size_t)t*720 + tau];
  BTm[(size_t)t*KP + tau] = __float2bfloat16(0.3f*acc + mp);
}

// ---------------- R12: blocks [0,3072) = x transpose; [3072,7168) = Wpos repack (4 bn/block) ----------------
__global__ __launch_bounds__(256) void r12(const float* __restrict__ x, const float* __restrict__ Wp,
                                           __hip_bfloat16* __restrict__ Abig){
  __shared__ float tile[64][65];
  int tid=threadIdx.x;
  int blk = blockIdx.x;
  if (blk < 3072){
    int b = blk/24; int rem = blk%24;
    int t0 = (rem>>1)*64, n0 = (rem&1)*64;
    int c = tid & 63, r0 = tid >> 6;
    #pragma unroll
    for (int s=0;s<16;++s){
      int r = r0 + s*4;
      int t = t0 + r;
      tile[r][c] = (t<SEQ) ? x[((size_t)b*SEQ + t)*NCH + n0 + c] : 0.f;
    }
    __syncthreads();
    int nn0 = tid >> 4;
    int tq  = tid & 15;
    int tt  = t0 + tq*4;
    #pragma unroll
    for (int s=0;s<4;++s){
      int nn = nn0 + s*16;
      short4 v;
      v.x = b2s(tile[tq*4+0][nn]);
      v.y = b2s(tile[tq*4+1][nn]);
      v.z = b2s(tile[tq*4+2][nn]);
      v.w = b2s(tile[tq*4+3][nn]);
      __hip_bfloat16* dst = Abig + (size_t)(b*NCH + n0+nn)*KP + tt;
      if (tt+3 < SEQ){
        *reinterpret_cast<short4*>(dst) = v;
      } else {
        short sv[4] = {v.x, v.y, v.z, v.w};
        for (int j=0;j<4;++j) if (tt+j < SEQ) *reinterpret_cast<short*>(dst+j) = sv[j];
      }
    }
    return;
  }
  // Wpos: 4 bn per block
  int j = (tid & 63)*4;              // 0..252 step 4 -> covers 0..251*4? need 0..1007
  int lane4 = tid >> 6;              // 0..3 : sub-bn
  int bn = (blk - 3072)*4 + lane4;
  // each 64-lane group handles one bn, j = lane*4 covers [0,256); loop to cover 1008
  const float* src = Wp + (size_t)bn*KW;
  __hip_bfloat16* dstb = Abig + (size_t)bn*KP + SEQ;
  for (int jj = j; jj < KP-SEQ; jj += 256){
    float f0,f1,f2,f3;
    if (jj+3 < KW){
      float2 u = *reinterpret_cast<const float2*>(src+jj);
      float2 w = *reinterpret_cast<const float2*>(src+jj+2);
      f0=u.x; f1=u.y; f2=w.x; f3=w.y;
    } else {
      f0=(jj  <KW)?src[jj  ]:0.f; f1=(jj+1<KW)?src[jj+1]:0.f;
      f2=(jj+2<KW)?src[jj+2]:0.f; f3=(jj+3<KW)?src[jj+3]:0.f;
    }
    short4 v = { b2s(f0), b2s(f1), b2s(f2), b2s(f3) };
    *reinterpret_cast<short4*>(dstb + jj) = v;
  }
}

// ---------------- GEMM (round-8 proven: BK=32, natural mapping) ----------------
typedef __attribute__((ext_vector_type(8))) short bfrag_t;
typedef __attribute__((ext_vector_type(4))) float accf_t;
typedef __attribute__((address_space(1))) void gvoid;
typedef __attribute__((address_space(3))) void lvoid;

__device__ __forceinline__ void gload16(const void* g, void* l){
  __builtin_amdgcn_global_load_lds((gvoid*)(g), (lvoid*)(l), 16, 0, 0);
}

__global__ __launch_bounds__(256) void gemm_main(const __hip_bfloat16* __restrict__ BTm,
                                                 const __hip_bfloat16* __restrict__ Abig,
                                                 const float* __restrict__ bias,
                                                 float* __restrict__ out)
{
  __shared__ __hip_bfloat16 At[128*32];
  __shared__ __hip_bfloat16 Bt[128*32];
  int tid = threadIdx.x;
  int lane = tid & 63;
  int wv = tid >> 6;
  int wr = wv >> 1, wc = wv & 1;
  int t0 = blockIdx.y*128, bn0 = blockIdx.x*128;

  accf_t acc[4][4];
  #pragma unroll
  for (int i=0;i<4;++i)
    #pragma unroll
    for (int j=0;j<4;++j) acc[i][j] = (accf_t){0.f,0.f,0.f,0.f};

  int lin0 = tid, lin1 = 256+tid;
  int row0 = lin0>>2, ug0 = (lin0&3) ^ ((row0>>1)&3);
  int row1 = lin1>>2, ug1 = (lin1&3) ^ ((row1>>1)&3);
  const __hip_bfloat16* gA0 = BTm  + (size_t)(t0 +row0)*KP + ug0*8;
  const __hip_bfloat16* gA1 = BTm  + (size_t)(t0 +row1)*KP + ug1*8;
  const __hip_bfloat16* gB0 = Abig + (size_t)(bn0+row0)*KP + ug0*8;
  const __hip_bfloat16* gB1 = Abig + (size_t)(bn0+row1)*KP + ug1*8;
  char* lA0 = (char*)At + lin0*16; char* lA1 = (char*)At + lin1*16;
  char* lB0 = (char*)Bt + lin0*16; char* lB1 = (char*)Bt + lin1*16;

  int g = lane>>4;
  int arow = wr*64 + (lane&15);
  int brow = wc*64 + (lane&15);

  for (int ks=0; ks<KP/32; ++ks){
    int k0 = ks*32;
    gload16(gA0 + k0, lA0);
    gload16(gA1 + k0, lA1);
    gload16(gB0 + k0, lB0);
    gload16(gB1 + k0, lB1);
    __syncthreads();
    bfrag_t af[4], bb[4];
    #pragma unroll
    for (int mi=0;mi<4;++mi){
      int r = arow + mi*16;
      int uu = g ^ ((r>>1)&3);
      af[mi] = *(const bfrag_t*)((const char*)At + r*64 + uu*16);
    }
    #pragma unroll
    for (int ni=0;ni<4;++ni){
      int r = brow + ni*16;
      int uu = g ^ ((r>>1)&3);
      bb[ni] = *(const bfrag_t*)((const char*)Bt + r*64 + uu*16);
    }
    #pragma unroll
    for (int mi=0;mi<4;++mi)
      #pragma unroll
      for (int ni=0;ni<4;++ni)
        acc[mi][ni] = __builtin_amdgcn_mfma_f32_16x16x32_bf16(af[mi], bb[ni], acc[mi][ni], 0, 0, 0);
    __syncthreads();
  }

  #pragma unroll
  for (int mi=0;mi<4;++mi){
    int tbase = t0 + wr*64 + mi*16 + (lane>>4)*4;
    #pragma unroll
    for (int ni=0;ni<4;++ni){
      int col = bn0 + wc*64 + ni*16 + (lane&15);
      int b = col>>7, n = col&127;
      size_t obase = (size_t)b*(SEQ*NCH) + n;
      #pragma unroll
      for (int r=0;r<4;++r){
        int t = tbase + r;
        if (t<SEQ) out[obase + (size_t)t*NCH] = acc[mi][ni][r] + bias[t];
      }
    }
  }
}

extern "C" void kernel_launch(void* const* d_in, const int* in_sizes, int n_in,
                              void* d_out, int out_size, void* d_ws, size_t ws_size,
                              hipStream_t stream)
{
  const float* x     = (const float*)d_in[0];
  const float* fqWr  = (const float*)d_in[1];
  const float* fqWi  = (const float*)d_in[2];
  const float* fqbr  = (const float*)d_in[3];
  const float* fqbi  = (const float*)d_in[4];
  const float* WPW   = (const float*)d_in[5];
  const float* WPb   = (const float*)d_in[6];
  const float* Wpos  = (const float*)d_in[7];
  const float* m1r   = (const float*)d_in[8];
  const float* m1i   = (const float*)d_in[9];
  const float* m1br  = (const float*)d_in[10];
  const float* m1bi  = (const float*)d_in[11];
  const float* fxr   = (const float*)d_in[12];
  const float* fxi   = (const float*)d_in[13];
  const float* fxbr  = (const float*)d_in[14];
  const float* fxbi  = (const float*)d_in[15];
  const float* pjr   = (const float*)d_in[16];
  const float* pji   = (const float*)d_in[17];
  const float* pjbr  = (const float*)d_in[18];
  const float* pjbi  = (const float*)d_in[19];
  const float* headW = (const float*)d_in[20];
  const float* headb = (const float*)d_in[21];

  char* ws = (char*)d_ws;
  size_t off = 0;
  auto alloc = [&](size_t bytes)->void*{ void* p = ws + off; off += (bytes + 255) & ~(size_t)255; return p; };
  __hip_bfloat16* Abig = (__hip_bfloat16*)alloc((size_t)BN*KP*2);
  __hip_bfloat16* BTm  = (__hip_bfloat16*)alloc((size_t)MT*KP*2);
  float* A1r = (float*)alloc((size_t)DOM*720*4);
  float* A1i = (float*)alloc((size_t)DOM*720*4);
  float* Mper= (float*)alloc((size_t)SEQ*720*4);
  cf* C   = (cf*)alloc((size_t)FRQ*PER*8);
  cf* PM  = (cf*)alloc((size_t)POUT*PIN*8);
  cf* M2  = (cf*)alloc((size_t)FRQ*FRQ*8);
  cf* o3b = (cf*)alloc((size_t)FRQ*POUT*8);
  float* bias = (float*)alloc((size_t)SEQ*4);

  p15<<<DOM+1,256,0,stream>>>(WPW,WPb, m1r,m1i,m1br,m1bi, fxr,fxi,fxbr,fxbi, pjr,pji,pjbr,pjbi,
                              fqWr,fqWi, C,PM,M2,o3b, A1r,A1i);
  r12<<<7168,256,0,stream>>>(x, Wpos, Abig);
  p_big2<<<SEQ,256,0,stream>>>(headW, PM, M2, o3b, C, fqbr, fqbi, headb, Mper, BTm, bias);
  p5m2<<<dim3(45,45),256,0,stream>>>(A1r, A1i, Mper, BTm);
  gemm_main<<<dim3(128, 6), 256, 0, stream>>>(BTm, Abig, bias, (float*)d_out);
}

// Round 12
// 156.435 us; speedup vs baseline: 1.3224x; 1.1223x over previous
//
#include <hip/hip_runtime.h>
#include <hip/hip_bf16.h>
#include <math.h>

#define SEQ 720
#define NCH 128
#define BATCH 128
#define BN 16384
#define DOM 72
#define PIN 30
#define POUT 30
#define FRQ 33
#define EMB 64
#define PER 24
#define KW 990
#define KP 1728
#define MT 768
#define PI_F 3.14159265358979323846f

typedef float2 cf;
__device__ __forceinline__ cf cmac(cf acc, cf a, cf b){
  acc.x += a.x*b.x - a.y*b.y; acc.y += a.x*b.y + a.y*b.x; return acc;
}
__device__ __forceinline__ short b2s(float f){
  __hip_bfloat16 h = __float2bfloat16(f);
  return *reinterpret_cast<short*>(&h);
}

// ---------------- P15: block 72 = p1 weight-composition; blocks 0..71 = p5 A1 rows ----------------
__global__ __launch_bounds__(256) void p15(const float* __restrict__ WPW, const float* __restrict__ WPb,
                         const float* __restrict__ m1r, const float* __restrict__ m1i,
                         const float* __restrict__ m1br, const float* __restrict__ m1bi,
                         const float* __restrict__ fxr, const float* __restrict__ fxi,
                         const float* __restrict__ fxbr, const float* __restrict__ fxbi,
                         const float* __restrict__ pjr, const float* __restrict__ pji,
                         const float* __restrict__ pjbr, const float* __restrict__ pjbi,
                         const float* __restrict__ fqr, const float* __restrict__ fqi,
                         cf* C, cf* PM, cf* M2, cf* o3b,
                         float* __restrict__ A1r, float* __restrict__ A1i)
{
  __shared__ cf e64[64];
  __shared__ float sW[EMB*PER];
  __shared__ float sWb[EMB];
  __shared__ float sM1r[PIN*PIN], sM1i[PIN*PIN];
  __shared__ float sFxr[FRQ*FRQ], sFxi[FRQ*FRQ];
  __shared__ float sPjr[POUT*PIN], sPji[POUT*PIN];
  __shared__ float sB[6*33];
  __shared__ cf s_d[FRQ];
  __shared__ cf s_rs[PIN];
  __shared__ cf s_o1[FRQ*PIN];
  __shared__ cf s_o2[FRQ*PIN];
  __shared__ cf tbl[720];
  __shared__ cf wrow[DOM];

  int tid = threadIdx.x;
  if (blockIdx.x < DOM){
    int k = blockIdx.x;
    for (int m=tid;m<720;m+=256){ float s,c; sincosf(-2.f*PI_F*(float)m/720.f,&s,&c); tbl[m]=make_float2(c,s); }
    for (int j=tid;j<DOM;j+=256) wrow[j]=make_float2(fqr[k*DOM+j], fqi[k*DOM+j]);
    __syncthreads();
    for (int tau=tid; tau<720; tau+=256){
      cf acc=make_float2(0.f,0.f);
      for (int j=0;j<DOM;++j) acc = cmac(acc, wrow[j], tbl[(j*tau)%720]);
      A1r[k*720+tau]=acc.x;
      A1i[k*720+tau]=acc.y;
    }
    return;
  }
  if (tid < 64){ float s,c; sincosf(2.f*PI_F*tid/64.f, &s, &c); e64[tid] = make_float2(c, s); }
  for (int i=tid; i<EMB*PER; i+=256) sW[i]=WPW[i];
  if (tid < EMB) sWb[tid]=WPb[tid];
  for (int i=tid; i<PIN*PIN; i+=256){ sM1r[i]=m1r[i]; sM1i[i]=m1i[i]; sPjr[i]=pjr[i]; sPji[i]=pji[i]; }
  for (int i=tid; i<FRQ*FRQ; i+=256){ sFxr[i]=fxr[i]; sFxi[i]=fxi[i]; }
  if (tid < PIN)  { sB[tid]      = m1br[tid]; sB[33+tid]  = m1bi[tid]; }
  if (tid < FRQ)  { sB[66+tid]   = fxbr[tid]; sB[99+tid]  = fxbi[tid]; }
  if (tid < POUT) { sB[132+tid]  = pjbr[tid]; sB[165+tid] = pjbi[tid]; }
  __syncthreads();
  for (int idx=tid; idx<FRQ*PER; idx+=256){
    int f = idx/PER, i = idx%PER;
    cf acc = make_float2(0.f,0.f);
    #pragma unroll 8
    for (int o=0;o<EMB;++o){ cf e = e64[(f*o)&63]; float w = sW[o*PER+i]; acc.x += w*e.x; acc.y -= w*e.y; }
    C[idx] = acc;
  }
  for (int f=tid; f<FRQ; f+=256){
    cf acc = make_float2(0.f,0.f);
    #pragma unroll 8
    for (int o=0;o<EMB;++o){ cf e = e64[(f*o)&63]; acc.x += sWb[o]*e.x; acc.y -= sWb[o]*e.y; }
    s_d[f]=acc;
  }
  for (int idx=tid; idx<POUT*PIN; idx+=256){
    int q = idx/PIN, pp = idx%PIN;
    cf acc = make_float2(sPjr[q*PIN+pp], sPji[q*PIN+pp]);
    #pragma unroll 6
    for (int p=0;p<PIN;++p){
      cf a = make_float2(sPjr[q*PIN+p], sPji[q*PIN+p]);
      cf b = make_float2(sM1r[p*PIN+pp], sM1i[p*PIN+pp]);
      acc = cmac(acc, a, b);
    }
    PM[idx]=acc;
  }
  for (int idx=tid; idx<FRQ*FRQ; idx+=256){
    int f = idx/FRQ, ff = idx%FRQ;
    cf v = make_float2(sFxr[idx], sFxi[idx]); if (f==ff) v.x += 1.f;
    M2[idx]=v;
  }
  for (int p=tid; p<PIN; p+=256){
    cf acc = make_float2(1.f,0.f);
    #pragma unroll 6
    for (int pp=0;pp<PIN;++pp){ acc.x += sM1r[p*PIN+pp]; acc.y += sM1i[p*PIN+pp]; }
    s_rs[p]=acc;
  }
  __syncthreads();
  for (int idx=tid; idx<FRQ*PIN; idx+=256){
    int f = idx/PIN, p = idx%PIN;
    cf v = make_float2(0.f,0.f); v = cmac(v, s_d[f], s_rs[p]);
    v.x += sB[p]; v.y += sB[33+p];
    s_o1[idx]=v;
  }
  __syncthreads();
  for (int idx=tid; idx<FRQ*PIN; idx+=256){
    int f = idx/PIN, p = idx%PIN;
    cf acc = make_float2(sB[66+f], sB[99+f]);
    #pragma unroll 4
    for (int ff=0; ff<FRQ; ++ff){
      cf m2 = make_float2(sFxr[f*FRQ+ff], sFxi[f*FRQ+ff]); if (f==ff) m2.x += 1.f;
      acc = cmac(acc, m2, s_o1[ff*PIN+p]);
    }
    s_o2[idx]=acc;
  }
  __syncthreads();
  for (int idx=tid; idx<FRQ*POUT; idx+=256){
    int f = idx/POUT, q = idx%POUT;
    cf acc = make_float2(sB[132+q], sB[165+q]);
    #pragma unroll 6
    for (int p=0;p<PIN;++p){
      cf a = make_float2(sPjr[q*PIN+p], sPji[q*PIN+p]);
      acc = cmac(acc, a, s_o2[f*PIN+p]);
    }
    o3b[f*POUT+q]=acc;
  }
}

// ---------------- P_BIG2 (512 threads): per-t p2+p3+p4+p7 + p6's mper/Wpos-cols ----------------
__global__ __launch_bounds__(512) void p_big2(const float* __restrict__ hW,
                    const cf* __restrict__ PM, const cf* __restrict__ M2, const cf* __restrict__ o3b,
                    const cf* __restrict__ Cm,
                    const float* __restrict__ fbr, const float* __restrict__ fbi,
                    const float* __restrict__ headb,
                    float* __restrict__ Mper, __hip_bfloat16* __restrict__ BTm,
                    float* __restrict__ bias){
  __shared__ cf e64[64];
  __shared__ float shw[1920];     // phase A input; later aliased by sC (792 cf = 6336B < 7680B)
  __shared__ cf sHc[990];         // phase A out; phase D overwrites as sV
  __shared__ cf sV1[990];
  __shared__ cf sPM[POUT*PIN];
  __shared__ cf sM2[FRQ*FRQ];
  __shared__ cf sO3[FRQ*POUT];
  __shared__ float red[512];
  cf* sC = (cf*)shw;
  cf* sV = sHc;
  int tid=threadIdx.x; int t=blockIdx.x;
  if (tid<64){ float s,c; sincosf(2.f*PI_F*tid/64.f,&s,&c); e64[tid]=make_float2(c,s); }
  for (int i=tid;i<1920;i+=512) shw[i]=hW[(size_t)t*1920+i];
  for (int i=tid;i<POUT*PIN;i+=512) sPM[i]=PM[i];
  for (int i=tid;i<FRQ*FRQ;i+=512) sM2[i]=M2[i];
  for (int i=tid;i<FRQ*POUT;i+=512) sO3[i]=o3b[i];
  __syncthreads();
  // A: Hc[q][f] from shw
  for (int idx=tid; idx<990; idx+=512){
    int q=idx/FRQ, f=idx%FRQ;
    cf acc=make_float2(0.f,0.f);
    const float* hw = &shw[q*64];
    #pragma unroll 8
    for (int o=0;o<EMB;++o){ cf e=e64[(f*o)&63]; float w=hw[o]; acc.x+=w*e.x; acc.y+=w*e.y; }
    float s=((f==0)||(f==32))?(1.f/64.f):(2.f/64.f);
    sHc[idx]=make_float2(acc.x*s, acc.y*s);
  }
  __syncthreads();   // shw consumed; sHc ready
  // B: V1 from sHc ; bias partial from sHc ; load sC (overwrites shw, safe)
  for (int idx=tid; idx<990; idx+=512){
    int f=idx/PIN, p=idx%PIN;
    cf acc=make_float2(0.f,0.f);
    #pragma unroll 6
    for (int q=0;q<POUT;++q) acc=cmac(acc, sHc[q*FRQ+f], sPM[q*PIN+p]);
    sV1[idx]=acc;
  }
  float part=0.f;
  for (int idx=tid; idx<990; idx+=512){
    int q=idx/FRQ, f=idx%FRQ;
    cf h=sHc[idx]; cf o=sO3[f*POUT+q];
    part += h.x*o.x - h.y*o.y;
  }
  part *= 0.7f;
  if (tid<DOM){
    int m=(tid*t)%720; float s,c; sincosf(2.f*PI_F*(float)m/720.f,&s,&c);
    float sc=(tid==0)?(1.f/720.f):(2.f/720.f);
    part += 0.3f*sc*(c*fbr[tid] - s*fbi[tid]);
  }
  for (int i=tid;i<FRQ*PER;i+=512) sC[i]=Cm[i];
  red[tid]=part; __syncthreads();
  for (int s=256;s>0;s>>=1){ if (tid<s) red[tid]+=red[tid+s]; __syncthreads(); }
  if (tid==0) bias[t] = red[0] + 0.7f*headb[t];
  __syncthreads();   // all sHc reads done; sC loaded
  // D: V[ff][pp] -> sV (aliases sHc)
  for (int idx=tid; idx<990; idx+=512){
    int ff=idx/PIN, pp=idx%PIN;
    cf acc=make_float2(0.f,0.f);
    #pragma unroll 4
    for (int f=0;f<FRQ;++f) acc=cmac(acc, sV1[f*PIN+pp], sM2[f*FRQ+ff]);
    sV[idx]=acc;
  }
  __syncthreads();
  // E: mper + Wpos columns
  for (int tau=tid; tau<720; tau+=512){
    int p0 = tau/PER, i0 = tau - p0*PER;
    float mper=0.f;
    #pragma unroll 4
    for (int f=0; f<FRQ; ++f){ cf v=sV[f*PIN+p0]; cf c=sC[f*PER+i0]; mper += v.x*c.x - v.y*c.y; }
    Mper[(size_t)t*720 + tau] = 0.7f*mper;
  }
  for (int j=tid;j<KP-SEQ;j+=512){
    float v = 0.f;
    if (j < KW){ int p=j/FRQ, f=j-p*FRQ; v = 0.7f * sV[f*PIN+p].x; }
    BTm[(size_t)t*KP + SEQ + j] = __float2bfloat16(v);
  }
}

// ---------------- P5M2: Mlow tile + join with Mper -> BTm[:,0:720] ----------------
__global__ __launch_bounds__(256) void p5m2(const float* __restrict__ A1r,
                                            const float* __restrict__ A1i,
                                            const float* __restrict__ Mper,
                                            __hip_bfloat16* __restrict__ BTm){
  __shared__ float sG[16*144];
  __shared__ float sA[144*16];
  int t0 = blockIdx.y*16, tau0 = blockIdx.x*16;
  int tid = threadIdx.x;
  for (int i=tid; i<16*72; i+=256){
    int tt=i/72, k=i%72;
    int m = ((t0+tt)*k) % 720;
    float s,c; sincosf(2.f*PI_F*(float)m/720.f,&s,&c);
    float sc = (k==0)?(1.f/720.f):(2.f/720.f);
    sG[tt*144+k]    = c*sc;
    sG[tt*144+72+k] = s*sc;
  }
  for (int i=tid; i<72*16; i+=256){
    int k=i/16, tc=i%16;
    sA[k*16+tc]      = A1r[k*720+tau0+tc];
    sA[(72+k)*16+tc] = A1i[k*720+tau0+tc];
  }
  __syncthreads();
  int tt=tid/16, tc=tid%16;
  float acc=0.f;
  #pragma unroll 8
  for (int k=0;k<72;++k)
    acc += sG[tt*144+k]*sA[k*16+tc] - sG[tt*144+72+k]*sA[(72+k)*16+tc];
  int t = t0+tt, tau = tau0+tc;
  float mp = Mper[(size_t)t*720 + tau];
  BTm[(size_t)t*KP + tau] = __float2bfloat16(0.3f*acc + mp);
}

// ---------------- R12: blocks [0,3072) = x transpose; [3072,7168) = Wpos repack (4 bn/block) ----------------
__global__ __launch_bounds__(256) void r12(const float* __restrict__ x, const float* __restrict__ Wp,
                                           __hip_bfloat16* __restrict__ Abig){
  __shared__ float tile[64][65];
  int tid=threadIdx.x;
  int blk = blockIdx.x;
  if (blk < 3072){
    int b = blk/24; int rem = blk%24;
    int t0 = (rem>>1)*64, n0 = (rem&1)*64;
    int c = tid & 63, r0 = tid >> 6;
    #pragma unroll
    for (int s=0;s<16;++s){
      int r = r0 + s*4;
      int t = t0 + r;
      tile[r][c] = (t<SEQ) ? x[((size_t)b*SEQ + t)*NCH + n0 + c] : 0.f;
    }
    __syncthreads();
    int nn0 = tid >> 4;
    int tq  = tid & 15;
    int tt  = t0 + tq*4;
    #pragma unroll
    for (int s=0;s<4;++s){
      int nn = nn0 + s*16;
      short4 v;
      v.x = b2s(tile[tq*4+0][nn]);
      v.y = b2s(tile[tq*4+1][nn]);
      v.z = b2s(tile[tq*4+2][nn]);
      v.w = b2s(tile[tq*4+3][nn]);
      __hip_bfloat16* dst = Abig + (size_t)(b*NCH + n0+nn)*KP + tt;
      if (tt+3 < SEQ){
        *reinterpret_cast<short4*>(dst) = v;
      } else {
        short sv[4] = {v.x, v.y, v.z, v.w};
        for (int j=0;j<4;++j) if (tt+j < SEQ) *reinterpret_cast<short*>(dst+j) = sv[j];
      }
    }
    return;
  }
  int j = (tid & 63)*4;
  int lane4 = tid >> 6;
  int bn = (blk - 3072)*4 + lane4;
  const float* src = Wp + (size_t)bn*KW;
  __hip_bfloat16* dstb = Abig + (size_t)bn*KP + SEQ;
  for (int jj = j; jj < KP-SEQ; jj += 256){
    float f0,f1,f2,f3;
    if (jj+3 < KW){
      float2 u = *reinterpret_cast<const float2*>(src+jj);
      float2 w = *reinterpret_cast<const float2*>(src+jj+2);
      f0=u.x; f1=u.y; f2=w.x; f3=w.y;
    } else {
      f0=(jj  <KW)?src[jj  ]:0.f; f1=(jj+1<KW)?src[jj+1]:0.f;
      f2=(jj+2<KW)?src[jj+2]:0.f; f3=(jj+3<KW)?src[jj+3]:0.f;
    }
    short4 v = { b2s(f0), b2s(f1), b2s(f2), b2s(f3) };
    *reinterpret_cast<short4*>(dstb + jj) = v;
  }
}

// ---------------- GEMM (round-8 proven: BK=32, natural mapping) ----------------
typedef __attribute__((ext_vector_type(8))) short bfrag_t;
typedef __attribute__((ext_vector_type(4))) float accf_t;
typedef __attribute__((address_space(1))) void gvoid;
typedef __attribute__((address_space(3))) void lvoid;

__device__ __forceinline__ void gload16(const void* g, void* l){
  __builtin_amdgcn_global_load_lds((gvoid*)(g), (lvoid*)(l), 16, 0, 0);
}

__global__ __launch_bounds__(256) void gemm_main(const __hip_bfloat16* __restrict__ BTm,
                                                 const __hip_bfloat16* __restrict__ Abig,
                                                 const float* __restrict__ bias,
                                                 float* __restrict__ out)
{
  __shared__ __hip_bfloat16 At[128*32];
  __shared__ __hip_bfloat16 Bt[128*32];
  int tid = threadIdx.x;
  int lane = tid & 63;
  int wv = tid >> 6;
  int wr = wv >> 1, wc = wv & 1;
  int t0 = blockIdx.y*128, bn0 = blockIdx.x*128;

  accf_t acc[4][4];
  #pragma unroll
  for (int i=0;i<4;++i)
    #pragma unroll
    for (int j=0;j<4;++j) acc[i][j] = (accf_t){0.f,0.f,0.f,0.f};

  int lin0 = tid, lin1 = 256+tid;
  int row0 = lin0>>2, ug0 = (lin0&3) ^ ((row0>>1)&3);
  int row1 = lin1>>2, ug1 = (lin1&3) ^ ((row1>>1)&3);
  const __hip_bfloat16* gA0 = BTm  + (size_t)(t0 +row0)*KP + ug0*8;
  const __hip_bfloat16* gA1 = BTm  + (size_t)(t0 +row1)*KP + ug1*8;
  const __hip_bfloat16* gB0 = Abig + (size_t)(bn0+row0)*KP + ug0*8;
  const __hip_bfloat16* gB1 = Abig + (size_t)(bn0+row1)*KP + ug1*8;
  char* lA0 = (char*)At + lin0*16; char* lA1 = (char*)At + lin1*16;
  char* lB0 = (char*)Bt + lin0*16; char* lB1 = (char*)Bt + lin1*16;

  int g = lane>>4;
  int arow = wr*64 + (lane&15);
  int brow = wc*64 + (lane&15);

  for (int ks=0; ks<KP/32; ++ks){
    int k0 = ks*32;
    gload16(gA0 + k0, lA0);
    gload16(gA1 + k0, lA1);
    gload16(gB0 + k0, lB0);
    gload16(gB1 + k0, lB1);
    __syncthreads();
    bfrag_t af[4], bb[4];
    #pragma unroll
    for (int mi=0;mi<4;++mi){
      int r = arow + mi*16;
      int uu = g ^ ((r>>1)&3);
      af[mi] = *(const bfrag_t*)((const char*)At + r*64 + uu*16);
    }
    #pragma unroll
    for (int ni=0;ni<4;++ni){
      int r = brow + ni*16;
      int uu = g ^ ((r>>1)&3);
      bb[ni] = *(const bfrag_t*)((const char*)Bt + r*64 + uu*16);
    }
    #pragma unroll
    for (int mi=0;mi<4;++mi)
      #pragma unroll
      for (int ni=0;ni<4;++ni)
        acc[mi][ni] = __builtin_amdgcn_mfma_f32_16x16x32_bf16(af[mi], bb[ni], acc[mi][ni], 0, 0, 0);
    __syncthreads();
  }

  #pragma unroll
  for (int mi=0;mi<4;++mi){
    int tbase = t0 + wr*64 + mi*16 + (lane>>4)*4;
    #pragma unroll
    for (int ni=0;ni<4;++ni){
      int col = bn0 + wc*64 + ni*16 + (lane&15);
      int b = col>>7, n = col&127;
      size_t obase = (size_t)b*(SEQ*NCH) + n;
      #pragma unroll
      for (int r=0;r<4;++r){
        int t = tbase + r;
        if (t<SEQ) out[obase + (size_t)t*NCH] = acc[mi][ni][r] + bias[t];
      }
    }
  }
}

extern "C" void kernel_launch(void* const* d_in, const int* in_sizes, int n_in,
                              void* d_out, int out_size, void* d_ws, size_t ws_size,
                              hipStream_t stream)
{
  const float* x     = (const float*)d_in[0];
  const float* fqWr  = (const float*)d_in[1];
  const float* fqWi  = (const float*)d_in[2];
  const float* fqbr  = (const float*)d_in[3];
  const float* fqbi  = (const float*)d_in[4];
  const float* WPW   = (const float*)d_in[5];
  const float* WPb   = (const float*)d_in[6];
  const float* Wpos  = (const float*)d_in[7];
  const float* m1r   = (const float*)d_in[8];
  const float* m1i   = (const float*)d_in[9];
  const float* m1br  = (const float*)d_in[10];
  const float* m1bi  = (const float*)d_in[11];
  const float* fxr   = (const float*)d_in[12];
  const float* fxi   = (const float*)d_in[13];
  const float* fxbr  = (const float*)d_in[14];
  const float* fxbi  = (const float*)d_in[15];
  const float* pjr   = (const float*)d_in[16];
  const float* pji   = (const float*)d_in[17];
  const float* pjbr  = (const float*)d_in[18];
  const float* pjbi  = (const float*)d_in[19];
  const float* headW = (const float*)d_in[20];
  const float* headb = (const float*)d_in[21];

  char* ws = (char*)d_ws;
  size_t off = 0;
  auto alloc = [&](size_t bytes)->void*{ void* p = ws + off; off += (bytes + 255) & ~(size_t)255; return p; };
  __hip_bfloat16* Abig = (__hip_bfloat16*)alloc((size_t)BN*KP*2);
  __hip_bfloat16* BTm  = (__hip_bfloat16*)alloc((size_t)MT*KP*2);
  float* A1r = (float*)alloc((size_t)DOM*720*4);
  float* A1i = (float*)alloc((size_t)DOM*720*4);
  float* Mper= (float*)alloc((size_t)SEQ*720*4);
  cf* C   = (cf*)alloc((size_t)FRQ*PER*8);
  cf* PM  = (cf*)alloc((size_t)POUT*PIN*8);
  cf* M2  = (cf*)alloc((size_t)FRQ*FRQ*8);
  cf* o3b = (cf*)alloc((size_t)FRQ*POUT*8);
  float* bias = (float*)alloc((size_t)SEQ*4);

  p15<<<DOM+1,256,0,stream>>>(WPW,WPb, m1r,m1i,m1br,m1bi, fxr,fxi,fxbr,fxbi, pjr,pji,pjbr,pjbi,
                              fqWr,fqWi, C,PM,M2,o3b, A1r,A1i);
  r12<<<7168,256,0,stream>>>(x, Wpos, Abig);
  p_big2<<<SEQ,512,0,stream>>>(headW, PM, M2, o3b, C, fqbr, fqbi, headb, Mper, BTm, bias);
  p5m2<<<dim3(45,45),256,0,stream>>>(A1r, A1i, Mper, BTm);
  gemm_main<<<dim3(128, 6), 256, 0, stream>>>(BTm, Abig, bias, (float*)d_out);
}

// Round 13
// 147.783 us; speedup vs baseline: 1.3998x; 1.0585x over previous
//
#include <hip/hip_runtime.h>
#include <hip/hip_bf16.h>
#include <math.h>

#define SEQ 720
#define NCH 128
#define BATCH 128
#define BN 16384
#define DOM 72
#define PIN 30
#define POUT 30
#define FRQ 33
#define EMB 64
#define PER 24
#define KW 990
#define KP 1728
#define MT 768
#define PI_F 3.14159265358979323846f

typedef float2 cf;
__device__ __forceinline__ cf cmac(cf acc, cf a, cf b){
  acc.x += a.x*b.x - a.y*b.y; acc.y += a.x*b.y + a.y*b.x; return acc;
}
__device__ __forceinline__ short b2s(float f){
  __hip_bfloat16 h = __float2bfloat16(f);
  return *reinterpret_cast<short*>(&h);
}

// ---------------- P15: block 72 = p1 weight-composition; blocks 0..71 = p5 A1 rows ----------------
__global__ __launch_bounds__(256) void p15(const float* __restrict__ WPW, const float* __restrict__ WPb,
                         const float* __restrict__ m1r, const float* __restrict__ m1i,
                         const float* __restrict__ m1br, const float* __restrict__ m1bi,
                         const float* __restrict__ fxr, const float* __restrict__ fxi,
                         const float* __restrict__ fxbr, const float* __restrict__ fxbi,
                         const float* __restrict__ pjr, const float* __restrict__ pji,
                         const float* __restrict__ pjbr, const float* __restrict__ pjbi,
                         const float* __restrict__ fqr, const float* __restrict__ fqi,
                         cf* C, cf* PM, cf* M2, cf* o3b,
                         float* __restrict__ A1r, float* __restrict__ A1i)
{
  __shared__ cf e64[64];
  __shared__ float sW[EMB*PER];
  __shared__ float sWb[EMB];
  __shared__ float sM1r[PIN*PIN], sM1i[PIN*PIN];
  __shared__ float sFxr[FRQ*FRQ], sFxi[FRQ*FRQ];
  __shared__ float sPjr[POUT*PIN], sPji[POUT*PIN];
  __shared__ float sB[6*33];
  __shared__ cf s_d[FRQ];
  __shared__ cf s_rs[PIN];
  __shared__ cf s_o1[FRQ*PIN];
  __shared__ cf s_o2[FRQ*PIN];
  __shared__ cf tbl[720];
  __shared__ cf wrow[DOM];

  int tid = threadIdx.x;
  if (blockIdx.x < DOM){
    int k = blockIdx.x;
    for (int m=tid;m<720;m+=256){ float s,c; sincosf(-2.f*PI_F*(float)m/720.f,&s,&c); tbl[m]=make_float2(c,s); }
    for (int j=tid;j<DOM;j+=256) wrow[j]=make_float2(fqr[k*DOM+j], fqi[k*DOM+j]);
    __syncthreads();
    for (int tau=tid; tau<720; tau+=256){
      cf acc=make_float2(0.f,0.f);
      for (int j=0;j<DOM;++j) acc = cmac(acc, wrow[j], tbl[(j*tau)%720]);
      A1r[k*720+tau]=acc.x;
      A1i[k*720+tau]=acc.y;
    }
    return;
  }
  if (tid < 64){ float s,c; sincosf(2.f*PI_F*tid/64.f, &s, &c); e64[tid] = make_float2(c, s); }
  for (int i=tid; i<EMB*PER; i+=256) sW[i]=WPW[i];
  if (tid < EMB) sWb[tid]=WPb[tid];
  for (int i=tid; i<PIN*PIN; i+=256){ sM1r[i]=m1r[i]; sM1i[i]=m1i[i]; sPjr[i]=pjr[i]; sPji[i]=pji[i]; }
  for (int i=tid; i<FRQ*FRQ; i+=256){ sFxr[i]=fxr[i]; sFxi[i]=fxi[i]; }
  if (tid < PIN)  { sB[tid]      = m1br[tid]; sB[33+tid]  = m1bi[tid]; }
  if (tid < FRQ)  { sB[66+tid]   = fxbr[tid]; sB[99+tid]  = fxbi[tid]; }
  if (tid < POUT) { sB[132+tid]  = pjbr[tid]; sB[165+tid] = pjbi[tid]; }
  __syncthreads();
  for (int idx=tid; idx<FRQ*PER; idx+=256){
    int f = idx/PER, i = idx%PER;
    cf acc = make_float2(0.f,0.f);
    #pragma unroll 8
    for (int o=0;o<EMB;++o){ cf e = e64[(f*o)&63]; float w = sW[o*PER+i]; acc.x += w*e.x; acc.y -= w*e.y; }
    C[idx] = acc;
  }
  for (int f=tid; f<FRQ; f+=256){
    cf acc = make_float2(0.f,0.f);
    #pragma unroll 8
    for (int o=0;o<EMB;++o){ cf e = e64[(f*o)&63]; acc.x += sWb[o]*e.x; acc.y -= sWb[o]*e.y; }
    s_d[f]=acc;
  }
  for (int idx=tid; idx<POUT*PIN; idx+=256){
    int q = idx/PIN, pp = idx%PIN;
    cf acc = make_float2(sPjr[q*PIN+pp], sPji[q*PIN+pp]);
    #pragma unroll 6
    for (int p=0;p<PIN;++p){
      cf a = make_float2(sPjr[q*PIN+p], sPji[q*PIN+p]);
      cf b = make_float2(sM1r[p*PIN+pp], sM1i[p*PIN+pp]);
      acc = cmac(acc, a, b);
    }
    PM[idx]=acc;
  }
  for (int idx=tid; idx<FRQ*FRQ; idx+=256){
    int f = idx/FRQ, ff = idx%FRQ;
    cf v = make_float2(sFxr[idx], sFxi[idx]); if (f==ff) v.x += 1.f;
    M2[idx]=v;
  }
  for (int p=tid; p<PIN; p+=256){
    cf acc = make_float2(1.f,0.f);
    #pragma unroll 6
    for (int pp=0;pp<PIN;++pp){ acc.x += sM1r[p*PIN+pp]; acc.y += sM1i[p*PIN+pp]; }
    s_rs[p]=acc;
  }
  __syncthreads();
  for (int idx=tid; idx<FRQ*PIN; idx+=256){
    int f = idx/PIN, p = idx%PIN;
    cf v = make_float2(0.f,0.f); v = cmac(v, s_d[f], s_rs[p]);
    v.x += sB[p]; v.y += sB[33+p];
    s_o1[idx]=v;
  }
  __syncthreads();
  for (int idx=tid; idx<FRQ*PIN; idx+=256){
    int f = idx/PIN, p = idx%PIN;
    cf acc = make_float2(sB[66+f], sB[99+f]);
    #pragma unroll 4
    for (int ff=0; ff<FRQ; ++ff){
      cf m2 = make_float2(sFxr[f*FRQ+ff], sFxi[f*FRQ+ff]); if (f==ff) m2.x += 1.f;
      acc = cmac(acc, m2, s_o1[ff*PIN+p]);
    }
    s_o2[idx]=acc;
  }
  __syncthreads();
  for (int idx=tid; idx<FRQ*POUT; idx+=256){
    int f = idx/POUT, q = idx%POUT;
    cf acc = make_float2(sB[132+q], sB[165+q]);
    #pragma unroll 6
    for (int p=0;p<PIN;++p){
      cf a = make_float2(sPjr[q*PIN+p], sPji[q*PIN+p]);
      acc = cmac(acc, a, s_o2[f*PIN+p]);
    }
    o3b[f*POUT+q]=acc;
  }
}

// ---------------- FUSED_MID (512 threads): blocks [0,720)=p_big3 (incl. Mlow join);
//                  [720,3792)=x transpose; [3792,5840)=Wpos repack ----------------
__global__ __launch_bounds__(512) void fused_mid(const float* __restrict__ hW,
                    const cf* __restrict__ PM, const cf* __restrict__ M2, const cf* __restrict__ o3b,
                    const cf* __restrict__ Cm,
                    const float* __restrict__ fbr, const float* __restrict__ fbi,
                    const float* __restrict__ headb,
                    const float* __restrict__ A1r, const float* __restrict__ A1i,
                    const float* __restrict__ x, const float* __restrict__ Wp,
                    __hip_bfloat16* __restrict__ BTm, float* __restrict__ bias,
                    __hip_bfloat16* __restrict__ Abig){
  __shared__ double smem_d[6336];   // 50688 B arena, manually unioned
  char* smem = (char*)smem_d;
  int tid = threadIdx.x;
  int blk = blockIdx.x;

  if (blk < SEQ){
    // ---------- p_big3 ----------
    cf*    e64 = (cf*)(smem + 0);        // 64 cf   = 512
    float* shw = (float*)(smem + 512);   // 1920 f  = 7680
    cf*    sHc = (cf*)(smem + 8192);     // 990 cf  = 7920
    cf*    sV1 = (cf*)(smem + 16112);    // 990 cf  = 7920
    cf*    sPM = (cf*)(smem + 24032);    // 900 cf  = 7200
    cf*    sM2 = (cf*)(smem + 31232);    // 1089 cf = 8712
    cf*    sO3 = (cf*)(smem + 39944);    // 990 cf  = 7920
    float* red = (float*)(smem + 47864); // 512 f   = 2048
    float* sG  = (float*)(smem + 49912); // 144 f   = 576  (Gr[0..71], Gi[72..143])
    cf* sC = (cf*)shw;                   // aliases shw after phase A
    cf* sV = sHc;                        // aliases sHc after phase B
    int t = blk;
    if (tid<64){ float s,c; sincosf(2.f*PI_F*tid/64.f,&s,&c); e64[tid]=make_float2(c,s); }
    if (tid<DOM){
      int m=(tid*t)%720; float s,c; sincosf(2.f*PI_F*(float)m/720.f,&s,&c);
      float sc=(tid==0)?(1.f/720.f):(2.f/720.f);
      sG[tid]=c*sc; sG[72+tid]=s*sc;
    }
    for (int i=tid;i<1920;i+=512) shw[i]=hW[(size_t)t*1920+i];
    for (int i=tid;i<POUT*PIN;i+=512) sPM[i]=PM[i];
    for (int i=tid;i<FRQ*FRQ;i+=512) sM2[i]=M2[i];
    for (int i=tid;i<FRQ*POUT;i+=512) sO3[i]=o3b[i];
    __syncthreads();
    // A: Hc[q][f]
    for (int idx=tid; idx<990; idx+=512){
      int q=idx/FRQ, f=idx%FRQ;
      cf acc=make_float2(0.f,0.f);
      const float* hw = &shw[q*64];
      #pragma unroll 8
      for (int o=0;o<EMB;++o){ cf e=e64[(f*o)&63]; float w=hw[o]; acc.x+=w*e.x; acc.y+=w*e.y; }
      float s=((f==0)||(f==32))?(1.f/64.f):(2.f/64.f);
      sHc[idx]=make_float2(acc.x*s, acc.y*s);
    }
    __syncthreads();   // shw consumed; sHc ready
    // B: V1 ; bias partial ; load sC (overwrites shw)
    for (int idx=tid; idx<990; idx+=512){
      int f=idx/PIN, p=idx%PIN;
      cf acc=make_float2(0.f,0.f);
      #pragma unroll 6
      for (int q=0;q<POUT;++q) acc=cmac(acc, sHc[q*FRQ+f], sPM[q*PIN+p]);
      sV1[idx]=acc;
    }
    float part=0.f;
    for (int idx=tid; idx<990; idx+=512){
      int q=idx/FRQ, f=idx%FRQ;
      cf h=sHc[idx]; cf o=sO3[f*POUT+q];
      part += h.x*o.x - h.y*o.y;
    }
    part *= 0.7f;
    if (tid<DOM){
      int m=(tid*t)%720; float s,c; sincosf(2.f*PI_F*(float)m/720.f,&s,&c);
      float sc=(tid==0)?(1.f/720.f):(2.f/720.f);
      part += 0.3f*sc*(c*fbr[tid] - s*fbi[tid]);
    }
    for (int i=tid;i<FRQ*PER;i+=512) sC[i]=Cm[i];
    red[tid]=part; __syncthreads();
    for (int s=256;s>0;s>>=1){ if (tid<s) red[tid]+=red[tid+s]; __syncthreads(); }
    if (tid==0) bias[t] = red[0] + 0.7f*headb[t];
    __syncthreads();   // sHc reads done; sC loaded
    // D: V[ff][pp] -> sV
    for (int idx=tid; idx<990; idx+=512){
      int ff=idx/PIN, pp=idx%PIN;
      cf acc=make_float2(0.f,0.f);
      #pragma unroll 4
      for (int f=0;f<FRQ;++f) acc=cmac(acc, sV1[f*PIN+pp], sM2[f*FRQ+ff]);
      sV[idx]=acc;
    }
    __syncthreads();
    // E: mper + Mlow join -> BTm[:,0:720] ; Wpos columns -> BTm[:,720:1728)
    for (int tau=tid; tau<720; tau+=512){
      int p0 = tau/PER, i0 = tau - p0*PER;
      float mper=0.f;
      #pragma unroll 4
      for (int f=0; f<FRQ; ++f){ cf v=sV[f*PIN+p0]; cf c=sC[f*PER+i0]; mper += v.x*c.x - v.y*c.y; }
      float mlow=0.f;
      #pragma unroll 8
      for (int k=0;k<DOM;++k)
        mlow += sG[k]*A1r[k*720+tau] - sG[72+k]*A1i[k*720+tau];
      BTm[(size_t)t*KP + tau] = __float2bfloat16(0.3f*mlow + 0.7f*mper);
    }
    for (int j=tid;j<KP-SEQ;j+=512){
      float v = 0.f;
      if (j < KW){ int p=j/FRQ, f=j-p*FRQ; v = 0.7f * sV[f*PIN+p].x; }
      BTm[(size_t)t*KP + SEQ + j] = __float2bfloat16(v);
    }
    return;
  }

  if (blk < SEQ + 3072){
    // ---------- x transpose: one 64x64 tile, 512 threads ----------
    float (*tile)[65] = (float(*)[65])smem;
    int bb = blk - SEQ;
    int b = bb/24; int rem = bb%24;
    int t0 = (rem>>1)*64, n0 = (rem&1)*64;
    int c = tid & 63, r0 = tid >> 6;   // r0 0..7
    #pragma unroll
    for (int s=0;s<8;++s){
      int r = r0 + s*8;
      int t = t0 + r;
      tile[r][c] = (t<SEQ) ? x[((size_t)b*SEQ + t)*NCH + n0 + c] : 0.f;
    }
    __syncthreads();
    int tq  = tid & 15;        // t-quad
    int nn0 = tid >> 4;        // 0..31
    int tt  = t0 + tq*4;
    #pragma unroll
    for (int s=0;s<2;++s){
      int nn = nn0 + s*32;
      short4 v;
      v.x = b2s(tile[tq*4+0][nn]);
      v.y = b2s(tile[tq*4+1][nn]);
      v.z = b2s(tile[tq*4+2][nn]);
      v.w = b2s(tile[tq*4+3][nn]);
      __hip_bfloat16* dst = Abig + (size_t)(b*NCH + n0+nn)*KP + tt;
      if (tt+3 < SEQ){
        *reinterpret_cast<short4*>(dst) = v;
      } else {
        short sv[4] = {v.x, v.y, v.z, v.w};
        for (int j=0;j<4;++j) if (tt+j < SEQ) *reinterpret_cast<short*>(dst+j) = sv[j];
      }
    }
    return;
  }

  // ---------- Wpos repack: 8 bn per block ----------
  {
    int bb = blk - SEQ - 3072;
    int lane8 = tid >> 6;          // 0..7
    int bn = bb*8 + lane8;
    int j = (tid & 63)*4;
    const float* src = Wp + (size_t)bn*KW;
    __hip_bfloat16* dstb = Abig + (size_t)bn*KP + SEQ;
    for (int jj = j; jj < KP-SEQ; jj += 256){
      float f0,f1,f2,f3;
      if (jj+3 < KW){
        float2 u = *reinterpret_cast<const float2*>(src+jj);
        float2 w = *reinterpret_cast<const float2*>(src+jj+2);
        f0=u.x; f1=u.y; f2=w.x; f3=w.y;
      } else {
        f0=(jj  <KW)?src[jj  ]:0.f; f1=(jj+1<KW)?src[jj+1]:0.f;
        f2=(jj+2<KW)?src[jj+2]:0.f; f3=(jj+3<KW)?src[jj+3]:0.f;
      }
      short4 v = { b2s(f0), b2s(f1), b2s(f2), b2s(f3) };
      *reinterpret_cast<short4*>(dstb + jj) = v;
    }
  }
}

// ---------------- GEMM (round-8 proven: BK=32, natural mapping) ----------------
typedef __attribute__((ext_vector_type(8))) short bfrag_t;
typedef __attribute__((ext_vector_type(4))) float accf_t;
typedef __attribute__((address_space(1))) void gvoid;
typedef __attribute__((address_space(3))) void lvoid;

__device__ __forceinline__ void gload16(const void* g, void* l){
  __builtin_amdgcn_global_load_lds((gvoid*)(g), (lvoid*)(l), 16, 0, 0);
}

__global__ __launch_bounds__(256) void gemm_main(const __hip_bfloat16* __restrict__ BTm,
                                                 const __hip_bfloat16* __restrict__ Abig,
                                                 const float* __restrict__ bias,
                                                 float* __restrict__ out)
{
  __shared__ __hip_bfloat16 At[128*32];
  __shared__ __hip_bfloat16 Bt[128*32];
  int tid = threadIdx.x;
  int lane = tid & 63;
  int wv = tid >> 6;
  int wr = wv >> 1, wc = wv & 1;
  int t0 = blockIdx.y*128, bn0 = blockIdx.x*128;

  accf_t acc[4][4];
  #pragma unroll
  for (int i=0;i<4;++i)
    #pragma unroll
    for (int j=0;j<4;++j) acc[i][j] = (accf_t){0.f,0.f,0.f,0.f};

  int lin0 = tid, lin1 = 256+tid;
  int row0 = lin0>>2, ug0 = (lin0&3) ^ ((row0>>1)&3);
  int row1 = lin1>>2, ug1 = (lin1&3) ^ ((row1>>1)&3);
  const __hip_bfloat16* gA0 = BTm  + (size_t)(t0 +row0)*KP + ug0*8;
  const __hip_bfloat16* gA1 = BTm  + (size_t)(t0 +row1)*KP + ug1*8;
  const __hip_bfloat16* gB0 = Abig + (size_t)(bn0+row0)*KP + ug0*8;
  const __hip_bfloat16* gB1 = Abig + (size_t)(bn0+row1)*KP + ug1*8;
  char* lA0 = (char*)At + lin0*16; char* lA1 = (char*)At + lin1*16;
  char* lB0 = (char*)Bt + lin0*16; char* lB1 = (char*)Bt + lin1*16;

  int g = lane>>4;
  int arow = wr*64 + (lane&15);
  int brow = wc*64 + (lane&15);

  for (int ks=0; ks<KP/32; ++ks){
    int k0 = ks*32;
    gload16(gA0 + k0, lA0);
    gload16(gA1 + k0, lA1);
    gload16(gB0 + k0, lB0);
    gload16(gB1 + k0, lB1);
    __syncthreads();
    bfrag_t af[4], bb[4];
    #pragma unroll
    for (int mi=0;mi<4;++mi){
      int r = arow + mi*16;
      int uu = g ^ ((r>>1)&3);
      af[mi] = *(const bfrag_t*)((const char*)At + r*64 + uu*16);
    }
    #pragma unroll
    for (int ni=0;ni<4;++ni){
      int r = brow + ni*16;
      int uu = g ^ ((r>>1)&3);
      bb[ni] = *(const bfrag_t*)((const char*)Bt + r*64 + uu*16);
    }
    #pragma unroll
    for (int mi=0;mi<4;++mi)
      #pragma unroll
      for (int ni=0;ni<4;++ni)
        acc[mi][ni] = __builtin_amdgcn_mfma_f32_16x16x32_bf16(af[mi], bb[ni], acc[mi][ni], 0, 0, 0);
    __syncthreads();
  }

  #pragma unroll
  for (int mi=0;mi<4;++mi){
    int tbase = t0 + wr*64 + mi*16 + (lane>>4)*4;
    #pragma unroll
    for (int ni=0;ni<4;++ni){
      int col = bn0 + wc*64 + ni*16 + (lane&15);
      int b = col>>7, n = col&127;
      size_t obase = (size_t)b*(SEQ*NCH) + n;
      #pragma unroll
      for (int r=0;r<4;++r){
        int t = tbase + r;
        if (t<SEQ) out[obase + (size_t)t*NCH] = acc[mi][ni][r] + bias[t];
      }
    }
  }
}

extern "C" void kernel_launch(void* const* d_in, const int* in_sizes, int n_in,
                              void* d_out, int out_size, void* d_ws, size_t ws_size,
                              hipStream_t stream)
{
  const float* x     = (const float*)d_in[0];
  const float* fqWr  = (const float*)d_in[1];
  const float* fqWi  = (const float*)d_in[2];
  const float* fqbr  = (const float*)d_in[3];
  const float* fqbi  = (const float*)d_in[4];
  const float* WPW   = (const float*)d_in[5];
  const float* WPb   = (const float*)d_in[6];
  const float* Wpos  = (const float*)d_in[7];
  const float* m1r   = (const float*)d_in[8];
  const float* m1i   = (const float*)d_in[9];
  const float* m1br  = (const float*)d_in[10];
  const float* m1bi  = (const float*)d_in[11];
  const float* fxr   = (const float*)d_in[12];
  const float* fxi   = (const float*)d_in[13];
  const float* fxbr  = (const float*)d_in[14];
  const float* fxbi  = (const float*)d_in[15];
  const float* pjr   = (const float*)d_in[16];
  const float* pji   = (const float*)d_in[17];
  const float* pjbr  = (const float*)d_in[18];
  const float* pjbi  = (const float*)d_in[19];
  const float* headW = (const float*)d_in[20];
  const float* headb = (const float*)d_in[21];

  char* ws = (char*)d_ws;
  size_t off = 0;
  auto alloc = [&](size_t bytes)->void*{ void* p = ws + off; off += (bytes + 255) & ~(size_t)255; return p; };
  __hip_bfloat16* Abig = (__hip_bfloat16*)alloc((size_t)BN*KP*2);
  __hip_bfloat16* BTm  = (__hip_bfloat16*)alloc((size_t)MT*KP*2);
  float* A1r = (float*)alloc((size_t)DOM*720*4);
  float* A1i = (float*)alloc((size_t)DOM*720*4);
  cf* C   = (cf*)alloc((size_t)FRQ*PER*8);
  cf* PM  = (cf*)alloc((size_t)POUT*PIN*8);
  cf* M2  = (cf*)alloc((size_t)FRQ*FRQ*8);
  cf* o3b = (cf*)alloc((size_t)FRQ*POUT*8);
  float* bias = (float*)alloc((size_t)SEQ*4);

  p15<<<DOM+1,256,0,stream>>>(WPW,WPb, m1r,m1i,m1br,m1bi, fxr,fxi,fxbr,fxbi, pjr,pji,pjbr,pjbi,
                              fqWr,fqWi, C,PM,M2,o3b, A1r,A1i);
  fused_mid<<<SEQ+3072+2048,512,0,stream>>>(headW, PM, M2, o3b, C, fqbr, fqbi, headb,
                                            A1r, A1i, x, Wpos, BTm, bias, Abig);
  gemm_main<<<dim3(128, 6), 256, 0, stream>>>(BTm, Abig, bias, (float*)d_out);
}